// Round 9
// baseline (2919.284 us; speedup 1.0000x reference)
//
#include <hip/hip_runtime.h>
#include <hip/hip_bf16.h>

// HeteroNet on MI355X — round 9.
// R8: conv2 still 412us; serial per-thread gather chains are structural (deg~3
// kills unrolling; occupancy tuning irrelevant). R9 replaces fused conv with:
//   k_msg (edge-parallel, 1 gather per wave program, TLP-hidden latency)
//   k_agg (node-parallel STREAMING reduction over CSR-ordered msg + MFMA update)
// msg materialized bf16 in a 69MB buffer, 2 node-chunks per direction.

#define NLn 50000
#define NPn 150000
#define En  500000
#define NBL 1563   // ceil(NLn/32)
#define NBP 4688   // ceil(NPn/32)
#define NBE_L 25000
#define NBE_P 75000
#define CAPE 270000          // msg buffer capacity (edges); chunks are ~250K +- 0.4K

typedef __attribute__((ext_vector_type(8))) short short8;
typedef __attribute__((ext_vector_type(4))) float float4v;

__device__ __forceinline__ float bf2f(unsigned short u){ return __uint_as_float(((unsigned)u) << 16); }
__device__ __forceinline__ float bflo(unsigned u){ return __uint_as_float(u << 16); }
__device__ __forceinline__ float bfhi(unsigned u){ return __uint_as_float(u & 0xffff0000u); }
__device__ __forceinline__ unsigned short f2bf(float f){
  __hip_bfloat16 h = __float2bfloat16(f);
  return *reinterpret_cast<unsigned short*>(&h);
}
// order-preserving float->uint; enc(v)>0 for all finite v, so 0 == "empty segment"
__device__ __forceinline__ unsigned encf(float f){
  unsigned u = __float_as_uint(f);
  return (u & 0x80000000u) ? ~u : (u | 0x80000000u);
}
__device__ __forceinline__ float tanh_fast(float x){
  return 1.f - 2.f/(__expf(2.f*x) + 1.f);
}

__global__ __launch_bounds__(256) void k_zero(unsigned* __restrict__ p, long n){
  long i = (long)blockIdx.x*256 + threadIdx.x;
  long stride = (long)gridDim.x*256;
  for (; i < n; i += stride) p[i] = 0u;
}

// merged embed: blocks [0,NBE_L): ligand; [NBE_L, NBE_L+NBE_P): protein
__global__ __launch_bounds__(256) void k_embed2(const float* __restrict__ Xl,
    const float* __restrict__ Xp, const float* __restrict__ Wn,
    unsigned short* __restrict__ outl, unsigned short* __restrict__ outp){
  bool isL = blockIdx.x < NBE_L;
  const float* X = isL ? Xl : Xp;
  unsigned short* out = isL ? outl : outp;
  int gid = (isL ? blockIdx.x : blockIdx.x - NBE_L)*256 + threadIdx.x;
  int n = gid >> 7, c = gid & 127;
  const float* xr = X + (size_t)n*44;
  float acc = 0.f;
  #pragma unroll
  for (int k=0;k<44;k++) acc += xr[k]*Wn[k*128+c];
  out[(size_t)n*128 + c] = f2bf(acc);
}

// v[j] = sum_r W_el[r] * W1[(256+r)*512 + j]
__global__ void k_vvec(const float* __restrict__ Wel, const float* __restrict__ W1,
                       float* __restrict__ v){
  int j = blockIdx.x*256 + threadIdx.x;
  if (j >= 512) return;
  float s = 0.f;
  #pragma unroll
  for (int r=0;r<8;r++) s += Wel[r]*W1[(256+r)*512 + j];
  v[j] = s;
}

__global__ __launch_bounds__(256) void k_w2t(const float* __restrict__ W2,
    unsigned short* __restrict__ w2t){
  int gid = blockIdx.x*256 + threadIdx.x;   // 65536
  int n = gid >> 9, k = gid & 511;
  w2t[n*512 + k] = f2bf(W2[k*128 + n]);
}
__global__ __launch_bounds__(256) void k_wmt(const float* __restrict__ Wm,
    unsigned short* __restrict__ wmt){
  int gid = blockIdx.x*256 + threadIdx.x;   // 16384
  int n = gid >> 7, k = gid & 127;
  wmt[n*128 + k] = f2bf(Wm[k*128 + n]);
}
__global__ __launch_bounds__(256) void k_wcat(const float* __restrict__ Ws,
    const float* __restrict__ Wn, unsigned short* __restrict__ wcat){
  int gid = blockIdx.x*256 + threadIdx.x;   // 196608
  int i = gid >> 15, rem = gid & 32767;
  int n = rem >> 8, k = rem & 255;
  float v = (k < 128) ? Ws[i*16384 + k*128 + n] : Wn[i*16384 + (k-128)*128 + n];
  wcat[gid] = f2bf(v);
}
__global__ __launch_bounds__(256) void k_w1t(const float* __restrict__ W1,
    unsigned short* __restrict__ w1t){
  int gid = blockIdx.x*256 + threadIdx.x;   // 131072 = 2*512*128
  int part = gid >> 16, rem = gid & 65535;
  int n = rem >> 7, k = rem & 127;
  w1t[gid] = f2bf(W1[(part*128 + k)*512 + n]);
}

// ---- CSR construction ----
__global__ __launch_bounds__(256) void k_count(const int* __restrict__ esrc,
    const int* __restrict__ edst, unsigned* __restrict__ cntL, unsigned* __restrict__ cntP){
  int e = blockIdx.x*256 + threadIdx.x;
  if (e >= En) return;
  atomicAdd(&cntL[esrc[e]], 1u);
  atomicAdd(&cntP[edst[e]], 1u);
}
__global__ __launch_bounds__(256) void k_chunkscan(const unsigned* __restrict__ cnt,
    unsigned* __restrict__ rowptr, unsigned* __restrict__ bsum, int n){
  __shared__ unsigned ts[256];
  int tid = threadIdx.x;
  int base = blockIdx.x*1024 + tid*4;
  unsigned v[4], run = 0;
  #pragma unroll
  for (int j=0;j<4;j++){ v[j] = run; run += (base+j < n) ? cnt[base+j] : 0u; }
  ts[tid] = run; __syncthreads();
  for (int off=1; off<256; off<<=1){
    unsigned t = (tid>=off) ? ts[tid-off] : 0u; __syncthreads();
    ts[tid] += t; __syncthreads();
  }
  unsigned excl = ts[tid] - run;
  #pragma unroll
  for (int j=0;j<4;j++) if (base+j < n) rowptr[base+j] = excl + v[j];
  if (tid == 255) bsum[blockIdx.x] = ts[255];
}
__global__ void k_scanb(unsigned* __restrict__ bsum, int nc){
  __shared__ unsigned ts[256];
  int tid = threadIdx.x;
  unsigned x = (tid < nc) ? bsum[tid] : 0u;
  ts[tid] = x; __syncthreads();
  for (int off=1; off<256; off<<=1){
    unsigned t = (tid>=off) ? ts[tid-off] : 0u; __syncthreads();
    ts[tid] += t; __syncthreads();
  }
  if (tid < nc) bsum[tid] = ts[tid] - x;
}
__global__ __launch_bounds__(256) void k_addoff(unsigned* __restrict__ rowptr,
    unsigned* __restrict__ cursor, const unsigned* __restrict__ bsum, int n){
  int i = blockIdx.x*256 + threadIdx.x;
  if (i < n){
    unsigned r = rowptr[i] + bsum[i>>10];
    rowptr[i] = r; cursor[i] = r;
  }
  if (i == 0) rowptr[n] = En;
}
// place edges into both CSR orders; store src/dst/d/batch only (rbf recomputed in k_msg)
__global__ __launch_bounds__(256) void k_place(const int* __restrict__ esrc,
    const int* __restrict__ edst, const float* __restrict__ ea,
    const int* __restrict__ lbatch, unsigned* __restrict__ curL,
    unsigned* __restrict__ curP, uint4* __restrict__ edgeL,
    int* __restrict__ srcP, float* __restrict__ dP){
  int e = blockIdx.x*256 + threadIdx.x;
  if (e >= En) return;
  int s = esrc[e], d = edst[e];
  float dd = ea[e];
  unsigned pl = atomicAdd(&curL[s], 1u);
  uint4 er; er.x = (unsigned)s; er.y = (unsigned)d;
  er.z = __float_as_uint(dd); er.w = (unsigned)lbatch[s];
  edgeL[pl] = er;
  unsigned pp = atomicAdd(&curP[d], 1u);
  srcP[pp] = s; dP[pp] = dd;
}

// ---- k_msg: edge-parallel message build for one chunk ----
// msg[p - e0][c] = silu(rbf(d_p)@Wb + bb)[c] * x_src[idx_p][c]   (bf16)
// 2 edges per 256-thread block; one gather per wave program.
__global__ __launch_bounds__(256) void k_msg(
    const unsigned short* __restrict__ xsrc,
    const int* __restrict__ eidx, int estride,
    const float* __restrict__ darr, int dstride,
    const float* __restrict__ Wb_i, const float* __restrict__ bb_i,
    const unsigned* __restrict__ rowptr, int nc0, int ncnt,
    unsigned short* __restrict__ msg){
  __shared__ float rbf[2][8];
  __shared__ int sn2[2];
  int e0 = (int)rowptr[nc0], e1 = (int)rowptr[nc0 + ncnt];
  int nE = e1 - e0; if (nE > CAPE) nE = CAPE;
  if ((int)blockIdx.x*2 >= nE) return;
  int tid = threadIdx.x, c = tid & 127, sub = tid >> 7;
  int e = e0 + blockIdx.x*2 + sub;
  if (e >= e0 + nE) e = e0 + nE - 1;
  if (c < 8){
    float dd = darr[(size_t)e*dstride];
    float a = (dd - 0.7142857143f*(float)c) * 1.6f;   // mu=linspace(0,5,8), sigma=5/8
    rbf[sub][c] = __expf(-a*a);
  }
  if (c == 8) sn2[sub] = eidx[(size_t)e*estride];
  __syncthreads();
  float s = bb_i[c];
  #pragma unroll
  for (int j=0;j<8;j++) s += rbf[sub][j]*Wb_i[j*128 + c];
  float base = s / (1.f + __expf(-s));                // silu
  float val = base * bf2f(xsrc[(size_t)sn2[sub]*128 + c]);
  msg[(size_t)(e - e0)*128 + c] = f2bf(val);
}

// ---- k_agg: streaming CSR aggregation + MFMA update for one chunk ----
// 32 nodes/block; thread (g,slot): g=channel-group of 8, slot covers 2 rows.
__global__ __launch_bounds__(256) void k_agg(
    const unsigned short* __restrict__ xdst_in,
    const unsigned short* __restrict__ msg,
    const unsigned* __restrict__ rowptr, int nc0, int ncnt, int ndst,
    const unsigned short* __restrict__ wcat, const float* __restrict__ bias,
    unsigned short* __restrict__ xout, unsigned short* __restrict__ xsum){
  __shared__ unsigned short ab[32][264];   // [m][k]: k<128 x_dst, k>=128 agg (bf16)
  __shared__ unsigned short ob[32][136];
  __shared__ unsigned rps[33];
  int tid = threadIdx.x;
  int nlim = nc0 + ncnt; if (nlim > ndst) nlim = ndst;
  int n0 = nc0 + blockIdx.x*32;
  if (tid < 33){
    int idx = n0 + tid; if (idx > nlim) idx = nlim;
    rps[tid] = rowptr[idx];
  }
  unsigned eb = rowptr[nc0];
  __syncthreads();

  // stage x_dst
  int c = tid & 127, hh = tid >> 7;
  for (int m = hh*16; m < hh*16+16; m++){
    int n = n0 + m;
    ab[m][c] = (n < nlim) ? xdst_in[(size_t)n*128 + c] : (unsigned short)0;
  }
  // streaming per-row reduction: 16 channel-groups x 16 slots
  int g = tid & 15, slot = tid >> 4;
  #pragma unroll
  for (int rr=0; rr<2; rr++){
    int m = slot*2 + rr;
    int n = n0 + m;
    float a0=0,a1=0,a2=0,a3=0,a4=0,a5=0,a6=0,a7=0;
    int dg = 1;
    if (n < nlim){
      unsigned q0 = rps[m] - eb, q1 = rps[m+1] - eb;
      dg = (int)(q1 - q0);
      if (q1 > CAPE) q1 = CAPE;
      if (q0 > CAPE) q0 = CAPE;
      const unsigned short* mp = msg + (size_t)q0*128 + g*8;
      for (unsigned p = q0; p < q1; p++, mp += 128){
        uint4 v = *(const uint4*)mp;
        a0 += bflo(v.x); a1 += bfhi(v.x);
        a2 += bflo(v.y); a3 += bfhi(v.y);
        a4 += bflo(v.z); a5 += bfhi(v.z);
        a6 += bflo(v.w); a7 += bfhi(v.w);
      }
    }
    float inv = 1.f / (float)(dg > 1 ? dg : 1);
    uint4 pk;
    pk.x = (unsigned)f2bf(a0*inv) | ((unsigned)f2bf(a1*inv) << 16);
    pk.y = (unsigned)f2bf(a2*inv) | ((unsigned)f2bf(a3*inv) << 16);
    pk.z = (unsigned)f2bf(a4*inv) | ((unsigned)f2bf(a5*inv) << 16);
    pk.w = (unsigned)f2bf(a6*inv) | ((unsigned)f2bf(a7*inv) << 16);
    *(uint4*)&ab[m][128 + g*8] = pk;
  }
  __syncthreads();

  // MFMA update: out = lrelu([x|agg] @ wcat + bias)
  int wave = tid >> 6, lane = tid & 63, quad = lane >> 4, l15 = lane & 15;
  int mt = wave & 1, nh = wave >> 1;
  int arow = mt*16 + l15;
  float4v acc[4] = {{0,0,0,0},{0,0,0,0},{0,0,0,0},{0,0,0,0}};
  for (int k0 = 0; k0 < 256; k0 += 32){
    short8 A = *(const short8*)&ab[arow][k0 + quad*8];
    #pragma unroll
    for (int nt=0;nt<4;nt++){
      short8 B = *(const short8*)&wcat[(size_t)(nh*64 + nt*16 + l15)*256 + k0 + quad*8];
      acc[nt] = __builtin_amdgcn_mfma_f32_16x16x32_bf16(A, B, acc[nt], 0, 0, 0);
    }
  }
  #pragma unroll
  for (int nt=0;nt<4;nt++){
    int col = nh*64 + nt*16 + l15;
    float bc = bias[col];
    #pragma unroll
    for (int r=0;r<4;r++){
      int row = mt*16 + quad*4 + r;
      float v = acc[nt][r] + bc;
      ob[row][col] = f2bf((v > 0.f) ? v : 0.01f*v);    // leaky_relu
    }
  }
  __syncthreads();
  for (int m = hh*16; m < hh*16+16; m++){
    int n = n0 + m;
    if (n < nlim){
      unsigned short vb = ob[m][c];
      size_t off = (size_t)n*128 + c;
      xout[off] = vb;
      xsum[off] = f2bf(bf2f(xsum[off]) + bf2f(vb));
    }
  }
}

// ---- merged MFMA hproj: blocks [0,NBL): ligand (+b1); [NBL,NBL+NBP): protein
__global__ __launch_bounds__(256) void k_hproj2(
    const unsigned short* __restrict__ xl_s, const unsigned short* __restrict__ xp_s,
    const unsigned short* __restrict__ w1t, const float* __restrict__ b1,
    unsigned* __restrict__ h_l, unsigned* __restrict__ h_p){
  __shared__ unsigned short hb[32][528];
  bool isL = blockIdx.x < NBL;
  const unsigned short* xs = isL ? xl_s : xp_s;
  const unsigned short* wt = isL ? w1t : w1t + 65536;
  unsigned* hout = isL ? h_l : h_p;
  int nn = isL ? NLn : NPn;
  int n0 = (isL ? blockIdx.x : blockIdx.x - NBL)*32;
  int tid = threadIdx.x;
  int wave = tid >> 6, lane = tid & 63, quad = lane >> 4, l15 = lane & 15;
  int mt = wave & 1, nh = wave >> 1;
  int an = n0 + mt*16 + l15; if (an >= nn) an = nn - 1;
  const unsigned short* aptr = xs + (size_t)an*128;
  float4v acc[16];
  #pragma unroll
  for (int i=0;i<16;i++) acc[i] = (float4v){0,0,0,0};
  for (int k0 = 0; k0 < 128; k0 += 32){
    short8 A = *(const short8*)&aptr[k0 + quad*8];
    #pragma unroll
    for (int nt=0;nt<16;nt++){
      short8 B = *(const short8*)&wt[(size_t)(nh*256 + nt*16 + l15)*128 + k0 + quad*8];
      acc[nt] = __builtin_amdgcn_mfma_f32_16x16x32_bf16(A, B, acc[nt], 0, 0, 0);
    }
  }
  #pragma unroll
  for (int nt=0;nt<16;nt++){
    int col = nh*256 + nt*16 + l15;
    float bv = isL ? b1[col] : 0.f;
    #pragma unroll
    for (int r=0;r<4;r++) hb[mt*16 + quad*4 + r][col] = f2bf(acc[nt][r] + bv);
  }
  __syncthreads();
  for (int m=0;m<32;m++){
    int n = n0 + m;
    if (n < nn){
      unsigned pack = (unsigned)hb[m][2*tid] | ((unsigned)hb[m][2*tid+1] << 16);
      hout[(size_t)n*256 + tid] = pack;
    }
  }
}

// ---- readout v3: 32 edges/block; coalesced LDS staging; (M32,N32) wave tiles;
//      m in registers; shuffle-butterfly flush. b1 pre-folded into h_l.
__global__ __launch_bounds__(256, 4) void k_readout3(
    const unsigned* __restrict__ hl, const unsigned* __restrict__ hp,
    const uint4* __restrict__ edgeL, const float* __restrict__ vvec,
    const unsigned short* __restrict__ w2t, const float* __restrict__ b2,
    const unsigned short* __restrict__ wmt, const float* __restrict__ bm,
    float* __restrict__ outw, unsigned* __restrict__ mmax){
  __shared__ __align__(16) char smem[33280];
  unsigned short (*hbuf)[520] = (unsigned short(*)[520])smem;   // dead after GEMM1
  unsigned short (*msb)[136]  = (unsigned short(*)[136])smem;   // aliases hbuf
  __shared__ int sidx[32], didx[32], bsh[32];
  __shared__ float dsts[32];
  int tid = threadIdx.x;
  int e0 = blockIdx.x*32;
  if (tid < 32){
    uint4 er = edgeL[e0 + tid];
    sidx[tid] = (int)er.x; didx[tid] = (int)er.y;
    dsts[tid] = __uint_as_float(er.z); bsh[tid] = (int)er.w;
  }
  __syncthreads();
  int j2 = tid*2;
  float2 vv = *(const float2*)&vvec[j2];
  #pragma unroll 8
  for (int i=0;i<32;i++){
    unsigned ua = hl[(size_t)sidx[i]*256 + tid];
    unsigned ub = hp[(size_t)didx[i]*256 + tid];
    float dd = dsts[i];
    float hx = fmaxf(bflo(ua) + bflo(ub) + dd*vv.x, 0.f);
    float hy = fmaxf(bfhi(ua) + bfhi(ub) + dd*vv.y, 0.f);
    *(unsigned*)&hbuf[i][j2] = (unsigned)f2bf(hx) | ((unsigned)f2bf(hy) << 16);
  }
  __syncthreads();
  int wave = tid >> 6, lane = tid & 63, quad = lane >> 4, l15 = lane & 15;
  int ns = wave*32;            // each wave: M=32 (all edges), N-strip of 32

  // GEMM1: m[32,128] = h[32,512] @ W2^T + b2
  float4v acc[2][2] = {{{0,0,0,0},{0,0,0,0}},{{0,0,0,0},{0,0,0,0}}};
  for (int k0 = 0; k0 < 512; k0 += 32){
    short8 A0 = *(const short8*)&hbuf[l15][k0 + quad*8];
    short8 A1 = *(const short8*)&hbuf[16 + l15][k0 + quad*8];
    short8 B0 = *(const short8*)&w2t[(size_t)(ns + l15)*512 + k0 + quad*8];
    short8 B1 = *(const short8*)&w2t[(size_t)(ns + 16 + l15)*512 + k0 + quad*8];
    acc[0][0] = __builtin_amdgcn_mfma_f32_16x16x32_bf16(A0, B0, acc[0][0], 0, 0, 0);
    acc[0][1] = __builtin_amdgcn_mfma_f32_16x16x32_bf16(A0, B1, acc[0][1], 0, 0, 0);
    acc[1][0] = __builtin_amdgcn_mfma_f32_16x16x32_bf16(A1, B0, acc[1][0], 0, 0, 0);
    acc[1][1] = __builtin_amdgcn_mfma_f32_16x16x32_bf16(A1, B1, acc[1][1], 0, 0, 0);
  }
  __syncthreads();   // all waves done reading hbuf; msb may overwrite
  float mreg[2][2][4];
  float b2c0 = b2[ns + l15], b2c1 = b2[ns + 16 + l15];
  #pragma unroll
  for (int mt=0;mt<2;mt++){
    #pragma unroll
    for (int nt=0;nt<2;nt++){
      float b2c = nt ? b2c1 : b2c0;
      int col = ns + nt*16 + l15;
      #pragma unroll
      for (int r=0;r<4;r++){
        float mv = acc[mt][nt][r] + b2c;
        mreg[mt][nt][r] = mv;
        msb[mt*16 + quad*4 + r][col] = f2bf(mv);
      }
    }
  }
  __syncthreads();

  // GEMM2: t = tanh(m@Wm^T + bm); flush sum(t*m), max(m) per batch
  float4v acc2[2][2] = {{{0,0,0,0},{0,0,0,0}},{{0,0,0,0},{0,0,0,0}}};
  for (int k0 = 0; k0 < 128; k0 += 32){
    short8 A0 = *(const short8*)&msb[l15][k0 + quad*8];
    short8 A1 = *(const short8*)&msb[16 + l15][k0 + quad*8];
    short8 B0 = *(const short8*)&wmt[(size_t)(ns + l15)*128 + k0 + quad*8];
    short8 B1 = *(const short8*)&wmt[(size_t)(ns + 16 + l15)*128 + k0 + quad*8];
    acc2[0][0] = __builtin_amdgcn_mfma_f32_16x16x32_bf16(A0, B0, acc2[0][0], 0, 0, 0);
    acc2[0][1] = __builtin_amdgcn_mfma_f32_16x16x32_bf16(A0, B1, acc2[0][1], 0, 0, 0);
    acc2[1][0] = __builtin_amdgcn_mfma_f32_16x16x32_bf16(A1, B0, acc2[1][0], 0, 0, 0);
    acc2[1][1] = __builtin_amdgcn_mfma_f32_16x16x32_bf16(A1, B1, acc2[1][1], 0, 0, 0);
  }
  float bm0 = bm[ns + l15], bm1 = bm[ns + 16 + l15];
  bool uni = (bsh[0] == bsh[31]);
  int b0 = bsh[0];
  #pragma unroll
  for (int nt=0;nt<2;nt++){
    int col = ns + nt*16 + l15;
    float bmc = nt ? bm1 : bm0;
    if (uni){
      float s = 0.f, mx = -3.402823466e38f;
      #pragma unroll
      for (int mt=0;mt<2;mt++){
        #pragma unroll
        for (int r=0;r<4;r++){
          float mv = mreg[mt][nt][r];
          float t = tanh_fast(acc2[mt][nt][r] + bmc);
          s += t*mv; mx = fmaxf(mx, mv);
        }
      }
      s += __shfl_xor(s, 16); s += __shfl_xor(s, 32);
      mx = fmaxf(mx, __shfl_xor(mx, 16)); mx = fmaxf(mx, __shfl_xor(mx, 32));
      if (quad == 0){
        atomicAdd(&outw[b0*256 + col], s);
        atomicMax(&mmax[b0*128 + col], encf(mx));
      }
    } else {
      #pragma unroll
      for (int mt=0;mt<2;mt++){
        #pragma unroll
        for (int r=0;r<4;r++){
          int row = mt*16 + quad*4 + r;
          int b = bsh[row];
          float mv = mreg[mt][nt][r];
          float t = tanh_fast(acc2[mt][nt][r] + bmc);
          atomicAdd(&outw[b*256 + col], t*mv);
          atomicMax(&mmax[b*128 + col], encf(mv));
        }
      }
    }
  }
}

__global__ __launch_bounds__(256) void k_final(const unsigned* __restrict__ mmax,
    float* __restrict__ out){
  int gid = blockIdx.x*256 + threadIdx.x;   // 32768 = 256*128
  unsigned enc = mmax[gid];
  float v;
  if (enc == 0u) v = 0.f;
  else if (enc & 0x80000000u) v = __uint_as_float(enc & 0x7FFFFFFFu);
  else v = __uint_as_float(~enc);
  int g = gid >> 7, cc = gid & 127;
  out[g*256 + 128 + cc] = v;
}

extern "C" void kernel_launch(void* const* d_in, const int* in_sizes, int n_in,
                              void* d_out, int out_size, void* d_ws, size_t ws_size,
                              hipStream_t stream) {
  const float* x_l    = (const float*)d_in[0];
  const float* x_p    = (const float*)d_in[1];
  const float* ea     = (const float*)d_in[2];
  const int*   esrc   = (const int*)d_in[3];
  const int*   edst   = (const int*)d_in[4];
  const int*   lbatch = (const int*)d_in[5];
  const float* W_node = (const float*)d_in[6];
  const float* W_el   = (const float*)d_in[7];
  const float* Wb     = (const float*)d_in[8];
  const float* bb     = (const float*)d_in[9];
  const float* Wn     = (const float*)d_in[10];
  const float* Ws     = (const float*)d_in[11];
  const float* bconv  = (const float*)d_in[12];
  const float* W1     = (const float*)d_in[13];
  const float* b1     = (const float*)d_in[14];
  const float* W2     = (const float*)d_in[15];
  const float* b2     = (const float*)d_in[16];
  const float* Wm     = (const float*)d_in[17];
  const float* bm     = (const float*)d_in[18];

  // ---- workspace layout (decimal offsets), peak 267,354,496 B (same as R4-8) ----
  char* w = (char*)d_ws;
  unsigned short* xl0 = (unsigned short*)(w + 0);
  unsigned short* xl1 = (unsigned short*)(w + 12800000);
  unsigned short* xp0 = (unsigned short*)(w + 25600000);
  unsigned short* xp1 = (unsigned short*)(w + 64000000);
  int*      srcP  = (int*)(w + 102400000);
  float*    dP    = (float*)(w + 104400000);
  unsigned short* msg = (unsigned short*)(w + 106400000);   // CAPE*256B = 69.12e6 -> 175.52e6
  unsigned* h_l   = (unsigned*)(w + 0);                     // readout phase aliases
  unsigned* h_p   = (unsigned*)(w + 51200000);
  unsigned short* xl_s = (unsigned short*)(w + 204800000);
  unsigned short* xp_s = (unsigned short*)(w + 217600000);
  unsigned short* wcat = (unsigned short*)(w + 256000000);
  unsigned short* w1t  = (unsigned short*)(w + 256393216);
  unsigned short* w2t  = (unsigned short*)(w + 256655360);
  unsigned short* wmt  = (unsigned short*)(w + 256786432);
  float*    vvec  = (float*)(w + 256819200);
  unsigned* mmax  = (unsigned*)(w + 256821248);
  unsigned* bsumL = (unsigned*)(w + 256952320);
  unsigned* bsumP = (unsigned*)(w + 256953344);
  unsigned* rowptrL = (unsigned*)(w + 256954368);
  unsigned* cursorL = (unsigned*)(w + 257154432);
  unsigned* rowptrP = (unsigned*)(w + 257354432);
  unsigned* cursorP = (unsigned*)(w + 257954496);
  unsigned* cntL    = (unsigned*)(w + 258554496);
  unsigned* cntP    = (unsigned*)(w + 258754496);
  uint4*    edgeL   = (uint4*)(w + 259354496);   // {src, dst, bits(d), batch}

  float* out = (float*)d_out;

  k_zero<<<1024, 256, 0, stream>>>((unsigned*)(w + 204800000), 51200000/4);  // xl_s+xp_s
  k_zero<<<196, 256, 0, stream>>>((unsigned*)(w + 258554496), 800000/4);     // cntL+cntP
  k_zero<<<128, 256, 0, stream>>>(mmax, 131072/4);
  k_zero<<<256, 256, 0, stream>>>((unsigned*)d_out, 262144/4);

  k_embed2<<<NBE_L + NBE_P, 256, 0, stream>>>(x_l, x_p, W_node, xl0, xp0);
  k_vvec<<<2, 256, 0, stream>>>(W_el, W1, vvec);
  k_w2t<<<256, 256, 0, stream>>>(W2, w2t);
  k_wmt<<<64, 256, 0, stream>>>(Wm, wmt);
  k_wcat<<<768, 256, 0, stream>>>(Ws, Wn, wcat);
  k_w1t<<<512, 256, 0, stream>>>(W1, w1t);

  k_count<<<1954, 256, 0, stream>>>(esrc, edst, cntL, cntP);
  k_chunkscan<<<49, 256, 0, stream>>>(cntL, rowptrL, bsumL, NLn);
  k_chunkscan<<<147, 256, 0, stream>>>(cntP, rowptrP, bsumP, NPn);
  k_scanb<<<1, 256, 0, stream>>>(bsumL, 49);
  k_scanb<<<1, 256, 0, stream>>>(bsumP, 147);
  k_addoff<<<196, 256, 0, stream>>>(rowptrL, cursorL, bsumL, NLn);
  k_addoff<<<586, 256, 0, stream>>>(rowptrP, cursorP, bsumP, NPn);
  k_place<<<1954, 256, 0, stream>>>(esrc, edst, ea, lbatch, cursorL, cursorP,
                                    edgeL, srcP, dP);

  const int* dstL = (const int*)edgeL + 1;     // edgeL[e].y, stride 4
  const float* dL = (const float*)edgeL + 2;   // edgeL[e].z, stride 4

  unsigned short *xlc = xl0, *xln = xl1, *xpc = xp0, *xpn = xp1;
  for (int l = 0; l < 3; ++l){
    int ilp = 2*l, ipl = 2*l + 1;
    // direction P (ligand->protein): dst=protein, gather ligand
    for (int h = 0; h < 2; ++h){
      k_msg<<<CAPE/2, 256, 0, stream>>>(xlc, srcP, 1, dP, 1,
          Wb + ilp*1024, bb + ilp*128, rowptrP, 75000*h, 75000, msg);
      k_agg<<<2344, 256, 0, stream>>>(xpc, msg, rowptrP, 75000*h, 75000, NPn,
          wcat + ilp*32768, bconv + ilp*128, xpn, xp_s);
    }
    // direction L (protein->ligand): dst=ligand, gather protein
    for (int h = 0; h < 2; ++h){
      k_msg<<<CAPE/2, 256, 0, stream>>>(xpc, dstL, 4, dL, 4,
          Wb + ipl*1024, bb + ipl*128, rowptrL, 25000*h, 25000, msg);
      k_agg<<<782, 256, 0, stream>>>(xlc, msg, rowptrL, 25000*h, 25000, NLn,
          wcat + ipl*32768, bconv + ipl*128, xln, xl_s);
    }
    unsigned short* t;
    t = xlc; xlc = xln; xln = t;
    t = xpc; xpc = xpn; xpn = t;
  }

  // b1 folded into h_l (ligand part); protein part no bias
  k_hproj2<<<NBL + NBP, 256, 0, stream>>>(xl_s, xp_s, w1t, b1, h_l, h_p);

  k_readout3<<<En/32, 256, 0, stream>>>(h_l, h_p, edgeL, vvec,
                                        w2t, b2, wmt, bm, out, mmax);
  k_final<<<128, 256, 0, stream>>>(mmax, out);
}

// Round 10
// 1831.401 us; speedup vs baseline: 1.5940x; 1.5940x over previous
//
#include <hip/hip_runtime.h>
#include <hip/hip_bf16.h>

// HeteroNet on MI355X — round 10.
// R9 (msg materialization) regressed -700us: 512MB/layer round-trip. Reverted.
// R10 = R7/R8 fused conv2 + silu-LUT: base_c(d)=silu(rbf(d)@Wb+bb)_c is a smooth
// scalar function of d -> 4096-bin x 128-ch x 6-conv bf16 LUT (6.3MB, built once).
// Bin packed into CSR edge index (idx | bin<<18). Inner loop: LDS idx read ->
// lut load + x gather -> FMA (~8 insts/visit vs ~25).

#define NLn 50000
#define NPn 150000
#define En  500000
#define NBL 1563   // ceil(NLn/32)
#define NBP 4688   // ceil(NPn/32)
#define NBE_L 25000
#define NBE_P 75000

typedef __attribute__((ext_vector_type(8))) short short8;
typedef __attribute__((ext_vector_type(4))) float float4v;

__device__ __forceinline__ float bf2f(unsigned short u){ return __uint_as_float(((unsigned)u) << 16); }
__device__ __forceinline__ float bflo(unsigned u){ return __uint_as_float(u << 16); }
__device__ __forceinline__ float bfhi(unsigned u){ return __uint_as_float(u & 0xffff0000u); }
__device__ __forceinline__ unsigned short f2bf(float f){
  __hip_bfloat16 h = __float2bfloat16(f);
  return *reinterpret_cast<unsigned short*>(&h);
}
// order-preserving float->uint; enc(v)>0 for all finite v, so 0 == "empty segment"
__device__ __forceinline__ unsigned encf(float f){
  unsigned u = __float_as_uint(f);
  return (u & 0x80000000u) ? ~u : (u | 0x80000000u);
}
__device__ __forceinline__ float tanh_fast(float x){
  return 1.f - 2.f/(__expf(2.f*x) + 1.f);
}

__global__ __launch_bounds__(256) void k_zero(unsigned* __restrict__ p, long n){
  long i = (long)blockIdx.x*256 + threadIdx.x;
  long stride = (long)gridDim.x*256;
  for (; i < n; i += stride) p[i] = 0u;
}

// merged embed: blocks [0,NBE_L): ligand; [NBE_L, NBE_L+NBE_P): protein
__global__ __launch_bounds__(256) void k_embed2(const float* __restrict__ Xl,
    const float* __restrict__ Xp, const float* __restrict__ Wn,
    unsigned short* __restrict__ outl, unsigned short* __restrict__ outp){
  bool isL = blockIdx.x < NBE_L;
  const float* X = isL ? Xl : Xp;
  unsigned short* out = isL ? outl : outp;
  int gid = (isL ? blockIdx.x : blockIdx.x - NBE_L)*256 + threadIdx.x;
  int n = gid >> 7, c = gid & 127;
  const float* xr = X + (size_t)n*44;
  float acc = 0.f;
  #pragma unroll
  for (int k=0;k<44;k++) acc += xr[k]*Wn[k*128+c];
  out[(size_t)n*128 + c] = f2bf(acc);
}

// v[j] = sum_r W_el[r] * W1[(256+r)*512 + j]
__global__ void k_vvec(const float* __restrict__ Wel, const float* __restrict__ W1,
                       float* __restrict__ v){
  int j = blockIdx.x*256 + threadIdx.x;
  if (j >= 512) return;
  float s = 0.f;
  #pragma unroll
  for (int r=0;r<8;r++) s += Wel[r]*W1[(256+r)*512 + j];
  v[j] = s;
}

__global__ __launch_bounds__(256) void k_w2t(const float* __restrict__ W2,
    unsigned short* __restrict__ w2t){
  int gid = blockIdx.x*256 + threadIdx.x;   // 65536
  int n = gid >> 9, k = gid & 511;
  w2t[n*512 + k] = f2bf(W2[k*128 + n]);
}
__global__ __launch_bounds__(256) void k_wmt(const float* __restrict__ Wm,
    unsigned short* __restrict__ wmt){
  int gid = blockIdx.x*256 + threadIdx.x;   // 16384
  int n = gid >> 7, k = gid & 127;
  wmt[n*128 + k] = f2bf(Wm[k*128 + n]);
}
__global__ __launch_bounds__(256) void k_wcat(const float* __restrict__ Ws,
    const float* __restrict__ Wn, unsigned short* __restrict__ wcat){
  int gid = blockIdx.x*256 + threadIdx.x;   // 196608
  int i = gid >> 15, rem = gid & 32767;
  int n = rem >> 8, k = rem & 255;
  float v = (k < 128) ? Ws[i*16384 + k*128 + n] : Wn[i*16384 + (k-128)*128 + n];
  wcat[gid] = f2bf(v);
}
__global__ __launch_bounds__(256) void k_w1t(const float* __restrict__ W1,
    unsigned short* __restrict__ w1t){
  int gid = blockIdx.x*256 + threadIdx.x;   // 131072 = 2*512*128
  int part = gid >> 16, rem = gid & 65535;
  int n = rem >> 7, k = rem & 127;
  w1t[gid] = f2bf(W1[(part*128 + k)*512 + n]);
}

// silu LUT: lut[i][bin][c] = bf16( silu( sum_j exp(-((d_bin-mu_j)*1.6)^2)*Wb[i][j][c] + bb[i][c] ) )
// 6 convs x 4096 bins x 128 ch; d_bin = (bin+0.5)*5/4096
__global__ __launch_bounds__(256) void k_lut(const float* __restrict__ Wb,
    const float* __restrict__ bb, unsigned short* __restrict__ lut){
  int gid = blockIdx.x*256 + threadIdx.x;   // 6*4096*128 = 3145728
  int c = gid & 127, bin = (gid >> 7) & 4095, i = gid >> 19;
  float d = ((float)bin + 0.5f) * 0.001220703125f;   // *5/4096
  float s = bb[i*128 + c];
  #pragma unroll
  for (int j=0;j<8;j++){
    float a = (d - 0.7142857143f*(float)j) * 1.6f;
    s += __expf(-a*a) * Wb[i*1024 + j*128 + c];
  }
  lut[gid] = f2bf(s / (1.f + __expf(-s)));
}

// ---- CSR construction ----
__global__ __launch_bounds__(256) void k_count(const int* __restrict__ esrc,
    const int* __restrict__ edst, unsigned* __restrict__ cntL, unsigned* __restrict__ cntP){
  int e = blockIdx.x*256 + threadIdx.x;
  if (e >= En) return;
  atomicAdd(&cntL[esrc[e]], 1u);
  atomicAdd(&cntP[edst[e]], 1u);
}
__global__ __launch_bounds__(256) void k_chunkscan(const unsigned* __restrict__ cnt,
    unsigned* __restrict__ rowptr, unsigned* __restrict__ bsum, int n){
  __shared__ unsigned ts[256];
  int tid = threadIdx.x;
  int base = blockIdx.x*1024 + tid*4;
  unsigned v[4], run = 0;
  #pragma unroll
  for (int j=0;j<4;j++){ v[j] = run; run += (base+j < n) ? cnt[base+j] : 0u; }
  ts[tid] = run; __syncthreads();
  for (int off=1; off<256; off<<=1){
    unsigned t = (tid>=off) ? ts[tid-off] : 0u; __syncthreads();
    ts[tid] += t; __syncthreads();
  }
  unsigned excl = ts[tid] - run;
  #pragma unroll
  for (int j=0;j<4;j++) if (base+j < n) rowptr[base+j] = excl + v[j];
  if (tid == 255) bsum[blockIdx.x] = ts[255];
}
__global__ void k_scanb(unsigned* __restrict__ bsum, int nc){
  __shared__ unsigned ts[256];
  int tid = threadIdx.x;
  unsigned x = (tid < nc) ? bsum[tid] : 0u;
  ts[tid] = x; __syncthreads();
  for (int off=1; off<256; off<<=1){
    unsigned t = (tid>=off) ? ts[tid-off] : 0u; __syncthreads();
    ts[tid] += t; __syncthreads();
  }
  if (tid < nc) bsum[tid] = ts[tid] - x;
}
__global__ __launch_bounds__(256) void k_addoff(unsigned* __restrict__ rowptr,
    unsigned* __restrict__ cursor, const unsigned* __restrict__ bsum, int n){
  int i = blockIdx.x*256 + threadIdx.x;
  if (i < n){
    unsigned r = rowptr[i] + bsum[i>>10];
    rowptr[i] = r; cursor[i] = r;
  }
  if (i == 0) rowptr[n] = En;
}
// place edges into both CSR orders; idx arrays packed with LUT bin (idx | bin<<18)
__global__ __launch_bounds__(256) void k_place(const int* __restrict__ esrc,
    const int* __restrict__ edst, const float* __restrict__ ea,
    const int* __restrict__ lbatch, unsigned* __restrict__ curL,
    unsigned* __restrict__ curP, uint4* __restrict__ edgeL,
    int* __restrict__ idxL, int* __restrict__ idxP){
  int e = blockIdx.x*256 + threadIdx.x;
  if (e >= En) return;
  int s = esrc[e], d = edst[e];
  float dd = ea[e];
  int bin = (int)(dd * 819.2f);
  bin = (bin < 0) ? 0 : ((bin > 4095) ? 4095 : bin);
  unsigned pl = atomicAdd(&curL[s], 1u);
  uint4 er; er.x = (unsigned)s; er.y = (unsigned)d;
  er.z = __float_as_uint(dd); er.w = (unsigned)lbatch[s];
  edgeL[pl] = er;
  idxL[pl] = d | (bin << 18);
  unsigned pp = atomicAdd(&curP[d], 1u);
  idxP[pp] = s | (bin << 18);
}

// ---- fused dual-direction conv with silu-LUT ----
// blocks [0,NBP): dst=protein (gather ligand); [NBP,NBP+NBL): dst=ligand
#define EDGE_CAP 1024
__global__ __launch_bounds__(256) void k_conv2(
    const unsigned short* __restrict__ xp_in, const unsigned short* __restrict__ xl_in,
    unsigned short* __restrict__ xp_out, unsigned short* __restrict__ xl_out,
    unsigned short* __restrict__ xp_sum, unsigned short* __restrict__ xl_sum,
    const unsigned* __restrict__ rowptrP, const int* __restrict__ idxP,
    const unsigned* __restrict__ rowptrL, const int* __restrict__ idxL,
    const unsigned short* __restrict__ lut_lp,
    const unsigned short* __restrict__ wcat_lp, const float* __restrict__ bias_lp,
    const unsigned short* __restrict__ lut_pl,
    const unsigned short* __restrict__ wcat_pl, const float* __restrict__ bias_pl){
  __shared__ unsigned short ab[32][264];   // [m][k]: k<128 x_dst, k>=128 agg (bf16)
  __shared__ unsigned short ob[32][136];   // epilogue bf16
  __shared__ int snb[EDGE_CAP];
  __shared__ unsigned rps[33];
  int tid = threadIdx.x, c = tid & 127, hh = tid >> 7;
  bool isP = blockIdx.x < NBP;
  const unsigned short* xdst_in = isP ? xp_in : xl_in;
  const unsigned short* xsrc_in = isP ? xl_in : xp_in;
  unsigned short* xout = isP ? xp_out : xl_out;
  unsigned short* xsum = isP ? xp_sum : xl_sum;
  const unsigned* rowptr = isP ? rowptrP : rowptrL;
  const int* eidx = isP ? idxP : idxL;
  const unsigned short* lut_i = isP ? lut_lp : lut_pl;
  const unsigned short* wcat = isP ? wcat_lp : wcat_pl;
  const float* bias = isP ? bias_lp : bias_pl;
  int ndst = isP ? NPn : NLn;
  int n0 = (isP ? blockIdx.x : (blockIdx.x - NBP)) * 32;

  if (tid < 33){
    int idx = n0 + tid; if (idx > ndst) idx = ndst;
    rps[tid] = rowptr[idx];
  }
  __syncthreads();
  int r00 = (int)rps[0], rEnd = (int)rps[32];
  int eblk = rEnd - r00;
  bool fits = (eblk <= EDGE_CAP);
  if (fits){
    for (int p = tid; p < eblk; p += 256) snb[p] = eidx[r00 + p];
  }
  __syncthreads();

  const unsigned short* lutc = lut_i + c;
  const unsigned short* xc = xsrc_in + c;
  for (int m = hh*16; m < hh*16+16; m++){
    int n = n0 + m;
    float a0=0.f, a1=0.f, a2=0.f, a3=0.f;
    int dg = 1;
    if (n < ndst){
      ab[m][c] = xdst_in[(size_t)n*128 + c];
      int r0 = (int)rps[m], r1 = (int)rps[m+1];
      dg = r1 - r0;
      int p = r0;
      for (; p + 3 < r1; p += 4){
        int v0,v1,v2,v3;
        if (fits){
          v0 = snb[p-r00]; v1 = snb[p-r00+1]; v2 = snb[p-r00+2]; v3 = snb[p-r00+3];
        } else {
          v0 = eidx[p]; v1 = eidx[p+1]; v2 = eidx[p+2]; v3 = eidx[p+3];
        }
        float b0 = bf2f(lutc[(size_t)((unsigned)v0 >> 18)*128]);
        float b1v = bf2f(lutc[(size_t)((unsigned)v1 >> 18)*128]);
        float b2v = bf2f(lutc[(size_t)((unsigned)v2 >> 18)*128]);
        float b3v = bf2f(lutc[(size_t)((unsigned)v3 >> 18)*128]);
        a0 += b0  * bf2f(xc[(size_t)(v0 & 0x3FFFF)*128]);
        a1 += b1v * bf2f(xc[(size_t)(v1 & 0x3FFFF)*128]);
        a2 += b2v * bf2f(xc[(size_t)(v2 & 0x3FFFF)*128]);
        a3 += b3v * bf2f(xc[(size_t)(v3 & 0x3FFFF)*128]);
      }
      for (; p < r1; p++){
        int v0 = fits ? snb[p-r00] : eidx[p];
        float b0 = bf2f(lutc[(size_t)((unsigned)v0 >> 18)*128]);
        a0 += b0 * bf2f(xc[(size_t)(v0 & 0x3FFFF)*128]);
      }
    } else {
      ab[m][c] = 0;
    }
    float inv = 1.f / (float)(dg > 1 ? dg : 1);
    ab[m][128 + c] = f2bf(((a0+a1)+(a2+a3)) * inv);
  }
  __syncthreads();

  int wave = tid >> 6, lane = tid & 63, quad = lane >> 4, l15 = lane & 15;
  int mt = wave & 1, nh = wave >> 1;
  int arow = mt*16 + l15;
  float4v acc[4] = {{0,0,0,0},{0,0,0,0},{0,0,0,0},{0,0,0,0}};
  for (int k0 = 0; k0 < 256; k0 += 32){
    short8 A = *(const short8*)&ab[arow][k0 + quad*8];
    #pragma unroll
    for (int nt=0;nt<4;nt++){
      short8 B = *(const short8*)&wcat[(size_t)(nh*64 + nt*16 + l15)*256 + k0 + quad*8];
      acc[nt] = __builtin_amdgcn_mfma_f32_16x16x32_bf16(A, B, acc[nt], 0, 0, 0);
    }
  }
  #pragma unroll
  for (int nt=0;nt<4;nt++){
    int col = nh*64 + nt*16 + l15;
    float bc = bias[col];
    #pragma unroll
    for (int r=0;r<4;r++){
      int row = mt*16 + quad*4 + r;
      float v = acc[nt][r] + bc;
      ob[row][col] = f2bf((v > 0.f) ? v : 0.01f*v);    // leaky_relu
    }
  }
  __syncthreads();
  for (int m = hh*16; m < hh*16+16; m++){
    int n = n0 + m;
    if (n < ndst){
      unsigned short vb = ob[m][c];
      size_t off = (size_t)n*128 + c;
      xout[off] = vb;
      xsum[off] = f2bf(bf2f(xsum[off]) + bf2f(vb));
    }
  }
}

// ---- merged MFMA hproj: blocks [0,NBL): ligand (+b1); [NBL,NBL+NBP): protein
__global__ __launch_bounds__(256) void k_hproj2(
    const unsigned short* __restrict__ xl_s, const unsigned short* __restrict__ xp_s,
    const unsigned short* __restrict__ w1t, const float* __restrict__ b1,
    unsigned* __restrict__ h_l, unsigned* __restrict__ h_p){
  __shared__ unsigned short hb[32][528];
  bool isL = blockIdx.x < NBL;
  const unsigned short* xs = isL ? xl_s : xp_s;
  const unsigned short* wt = isL ? w1t : w1t + 65536;
  unsigned* hout = isL ? h_l : h_p;
  int nn = isL ? NLn : NPn;
  int n0 = (isL ? blockIdx.x : blockIdx.x - NBL)*32;
  int tid = threadIdx.x;
  int wave = tid >> 6, lane = tid & 63, quad = lane >> 4, l15 = lane & 15;
  int mt = wave & 1, nh = wave >> 1;
  int an = n0 + mt*16 + l15; if (an >= nn) an = nn - 1;
  const unsigned short* aptr = xs + (size_t)an*128;
  float4v acc[16];
  #pragma unroll
  for (int i=0;i<16;i++) acc[i] = (float4v){0,0,0,0};
  for (int k0 = 0; k0 < 128; k0 += 32){
    short8 A = *(const short8*)&aptr[k0 + quad*8];
    #pragma unroll
    for (int nt=0;nt<16;nt++){
      short8 B = *(const short8*)&wt[(size_t)(nh*256 + nt*16 + l15)*128 + k0 + quad*8];
      acc[nt] = __builtin_amdgcn_mfma_f32_16x16x32_bf16(A, B, acc[nt], 0, 0, 0);
    }
  }
  #pragma unroll
  for (int nt=0;nt<16;nt++){
    int col = nh*256 + nt*16 + l15;
    float bv = isL ? b1[col] : 0.f;
    #pragma unroll
    for (int r=0;r<4;r++) hb[mt*16 + quad*4 + r][col] = f2bf(acc[nt][r] + bv);
  }
  __syncthreads();
  for (int m=0;m<32;m++){
    int n = n0 + m;
    if (n < nn){
      unsigned pack = (unsigned)hb[m][2*tid] | ((unsigned)hb[m][2*tid+1] << 16);
      hout[(size_t)n*256 + tid] = pack;
    }
  }
}

// ---- readout v3: 32 edges/block; coalesced LDS staging; (M32,N32) wave tiles;
//      m in registers; shuffle-butterfly flush. b1 pre-folded into h_l.
__global__ __launch_bounds__(256, 4) void k_readout3(
    const unsigned* __restrict__ hl, const unsigned* __restrict__ hp,
    const uint4* __restrict__ edgeL, const float* __restrict__ vvec,
    const unsigned short* __restrict__ w2t, const float* __restrict__ b2,
    const unsigned short* __restrict__ wmt, const float* __restrict__ bm,
    float* __restrict__ outw, unsigned* __restrict__ mmax){
  __shared__ __align__(16) char smem[33280];
  unsigned short (*hbuf)[520] = (unsigned short(*)[520])smem;   // dead after GEMM1
  unsigned short (*msb)[136]  = (unsigned short(*)[136])smem;   // aliases hbuf
  __shared__ int sidx[32], didx[32], bsh[32];
  __shared__ float dsts[32];
  int tid = threadIdx.x;
  int e0 = blockIdx.x*32;
  if (tid < 32){
    uint4 er = edgeL[e0 + tid];
    sidx[tid] = (int)er.x; didx[tid] = (int)er.y;
    dsts[tid] = __uint_as_float(er.z); bsh[tid] = (int)er.w;
  }
  __syncthreads();
  int j2 = tid*2;
  float2 vv = *(const float2*)&vvec[j2];
  #pragma unroll 8
  for (int i=0;i<32;i++){
    unsigned ua = hl[(size_t)sidx[i]*256 + tid];
    unsigned ub = hp[(size_t)didx[i]*256 + tid];
    float dd = dsts[i];
    float hx = fmaxf(bflo(ua) + bflo(ub) + dd*vv.x, 0.f);
    float hy = fmaxf(bfhi(ua) + bfhi(ub) + dd*vv.y, 0.f);
    *(unsigned*)&hbuf[i][j2] = (unsigned)f2bf(hx) | ((unsigned)f2bf(hy) << 16);
  }
  __syncthreads();
  int wave = tid >> 6, lane = tid & 63, quad = lane >> 4, l15 = lane & 15;
  int ns = wave*32;            // each wave: M=32 (all edges), N-strip of 32

  // GEMM1: m[32,128] = h[32,512] @ W2^T + b2
  float4v acc[2][2] = {{{0,0,0,0},{0,0,0,0}},{{0,0,0,0},{0,0,0,0}}};
  for (int k0 = 0; k0 < 512; k0 += 32){
    short8 A0 = *(const short8*)&hbuf[l15][k0 + quad*8];
    short8 A1 = *(const short8*)&hbuf[16 + l15][k0 + quad*8];
    short8 B0 = *(const short8*)&w2t[(size_t)(ns + l15)*512 + k0 + quad*8];
    short8 B1 = *(const short8*)&w2t[(size_t)(ns + 16 + l15)*512 + k0 + quad*8];
    acc[0][0] = __builtin_amdgcn_mfma_f32_16x16x32_bf16(A0, B0, acc[0][0], 0, 0, 0);
    acc[0][1] = __builtin_amdgcn_mfma_f32_16x16x32_bf16(A0, B1, acc[0][1], 0, 0, 0);
    acc[1][0] = __builtin_amdgcn_mfma_f32_16x16x32_bf16(A1, B0, acc[1][0], 0, 0, 0);
    acc[1][1] = __builtin_amdgcn_mfma_f32_16x16x32_bf16(A1, B1, acc[1][1], 0, 0, 0);
  }
  __syncthreads();   // all waves done reading hbuf; msb may overwrite
  float mreg[2][2][4];
  float b2c0 = b2[ns + l15], b2c1 = b2[ns + 16 + l15];
  #pragma unroll
  for (int mt=0;mt<2;mt++){
    #pragma unroll
    for (int nt=0;nt<2;nt++){
      float b2c = nt ? b2c1 : b2c0;
      int col = ns + nt*16 + l15;
      #pragma unroll
      for (int r=0;r<4;r++){
        float mv = acc[mt][nt][r] + b2c;
        mreg[mt][nt][r] = mv;
        msb[mt*16 + quad*4 + r][col] = f2bf(mv);
      }
    }
  }
  __syncthreads();

  // GEMM2: t = tanh(m@Wm^T + bm); flush sum(t*m), max(m) per batch
  float4v acc2[2][2] = {{{0,0,0,0},{0,0,0,0}},{{0,0,0,0},{0,0,0,0}}};
  for (int k0 = 0; k0 < 128; k0 += 32){
    short8 A0 = *(const short8*)&msb[l15][k0 + quad*8];
    short8 A1 = *(const short8*)&msb[16 + l15][k0 + quad*8];
    short8 B0 = *(const short8*)&wmt[(size_t)(ns + l15)*128 + k0 + quad*8];
    short8 B1 = *(const short8*)&wmt[(size_t)(ns + 16 + l15)*128 + k0 + quad*8];
    acc2[0][0] = __builtin_amdgcn_mfma_f32_16x16x32_bf16(A0, B0, acc2[0][0], 0, 0, 0);
    acc2[0][1] = __builtin_amdgcn_mfma_f32_16x16x32_bf16(A0, B1, acc2[0][1], 0, 0, 0);
    acc2[1][0] = __builtin_amdgcn_mfma_f32_16x16x32_bf16(A1, B0, acc2[1][0], 0, 0, 0);
    acc2[1][1] = __builtin_amdgcn_mfma_f32_16x16x32_bf16(A1, B1, acc2[1][1], 0, 0, 0);
  }
  float bm0 = bm[ns + l15], bm1 = bm[ns + 16 + l15];
  bool uni = (bsh[0] == bsh[31]);
  int b0 = bsh[0];
  #pragma unroll
  for (int nt=0;nt<2;nt++){
    int col = ns + nt*16 + l15;
    float bmc = nt ? bm1 : bm0;
    if (uni){
      float s = 0.f, mx = -3.402823466e38f;
      #pragma unroll
      for (int mt=0;mt<2;mt++){
        #pragma unroll
        for (int r=0;r<4;r++){
          float mv = mreg[mt][nt][r];
          float t = tanh_fast(acc2[mt][nt][r] + bmc);
          s += t*mv; mx = fmaxf(mx, mv);
        }
      }
      s += __shfl_xor(s, 16); s += __shfl_xor(s, 32);
      mx = fmaxf(mx, __shfl_xor(mx, 16)); mx = fmaxf(mx, __shfl_xor(mx, 32));
      if (quad == 0){
        atomicAdd(&outw[b0*256 + col], s);
        atomicMax(&mmax[b0*128 + col], encf(mx));
      }
    } else {
      #pragma unroll
      for (int mt=0;mt<2;mt++){
        #pragma unroll
        for (int r=0;r<4;r++){
          int row = mt*16 + quad*4 + r;
          int b = bsh[row];
          float mv = mreg[mt][nt][r];
          float t = tanh_fast(acc2[mt][nt][r] + bmc);
          atomicAdd(&outw[b*256 + col], t*mv);
          atomicMax(&mmax[b*128 + col], encf(mv));
        }
      }
    }
  }
}

__global__ __launch_bounds__(256) void k_final(const unsigned* __restrict__ mmax,
    float* __restrict__ out){
  int gid = blockIdx.x*256 + threadIdx.x;   // 32768 = 256*128
  unsigned enc = mmax[gid];
  float v;
  if (enc == 0u) v = 0.f;
  else if (enc & 0x80000000u) v = __uint_as_float(enc & 0x7FFFFFFFu);
  else v = __uint_as_float(~enc);
  int g = gid >> 7, cc = gid & 127;
  out[g*256 + 128 + cc] = v;
}

extern "C" void kernel_launch(void* const* d_in, const int* in_sizes, int n_in,
                              void* d_out, int out_size, void* d_ws, size_t ws_size,
                              hipStream_t stream) {
  const float* x_l    = (const float*)d_in[0];
  const float* x_p    = (const float*)d_in[1];
  const float* ea     = (const float*)d_in[2];
  const int*   esrc   = (const int*)d_in[3];
  const int*   edst   = (const int*)d_in[4];
  const int*   lbatch = (const int*)d_in[5];
  const float* W_node = (const float*)d_in[6];
  const float* W_el   = (const float*)d_in[7];
  const float* Wb     = (const float*)d_in[8];
  const float* bb     = (const float*)d_in[9];
  const float* Wn     = (const float*)d_in[10];
  const float* Ws     = (const float*)d_in[11];
  const float* bconv  = (const float*)d_in[12];
  const float* W1     = (const float*)d_in[13];
  const float* b1     = (const float*)d_in[14];
  const float* W2     = (const float*)d_in[15];
  const float* b2     = (const float*)d_in[16];
  const float* Wm     = (const float*)d_in[17];
  const float* bm     = (const float*)d_in[18];

  // ---- workspace layout (decimal offsets), peak 267,354,496 B ----
  // conv phase region A [0,204.8e6): xl0/xl1/xp0/xp1, idxP, idxL, lut
  // readout phase aliases: h_l [0,51.2e6), h_p [51.2e6,204.8e6)
  char* w = (char*)d_ws;
  unsigned short* xl0 = (unsigned short*)(w + 0);
  unsigned short* xl1 = (unsigned short*)(w + 12800000);
  unsigned short* xp0 = (unsigned short*)(w + 25600000);
  unsigned short* xp1 = (unsigned short*)(w + 64000000);
  int*      idxP  = (int*)(w + 102400000);
  int*      idxL  = (int*)(w + 104400000);
  unsigned short* lut = (unsigned short*)(w + 106400000);   // 6.29e6 B
  unsigned* h_l   = (unsigned*)(w + 0);
  unsigned* h_p   = (unsigned*)(w + 51200000);
  unsigned short* xl_s = (unsigned short*)(w + 204800000);
  unsigned short* xp_s = (unsigned short*)(w + 217600000);
  unsigned short* wcat = (unsigned short*)(w + 256000000);
  unsigned short* w1t  = (unsigned short*)(w + 256393216);
  unsigned short* w2t  = (unsigned short*)(w + 256655360);
  unsigned short* wmt  = (unsigned short*)(w + 256786432);
  float*    vvec  = (float*)(w + 256819200);
  unsigned* mmax  = (unsigned*)(w + 256821248);
  unsigned* bsumL = (unsigned*)(w + 256952320);
  unsigned* bsumP = (unsigned*)(w + 256953344);
  unsigned* rowptrL = (unsigned*)(w + 256954368);
  unsigned* cursorL = (unsigned*)(w + 257154432);
  unsigned* rowptrP = (unsigned*)(w + 257354432);
  unsigned* cursorP = (unsigned*)(w + 257954496);
  unsigned* cntL    = (unsigned*)(w + 258554496);
  unsigned* cntP    = (unsigned*)(w + 258754496);
  uint4*    edgeL   = (uint4*)(w + 259354496);   // {src, dst, bits(d), batch}

  float* out = (float*)d_out;

  k_zero<<<1024, 256, 0, stream>>>((unsigned*)(w + 204800000), 51200000/4);  // xl_s+xp_s
  k_zero<<<196, 256, 0, stream>>>((unsigned*)(w + 258554496), 800000/4);     // cntL+cntP
  k_zero<<<128, 256, 0, stream>>>(mmax, 131072/4);
  k_zero<<<256, 256, 0, stream>>>((unsigned*)d_out, 262144/4);

  k_embed2<<<NBE_L + NBE_P, 256, 0, stream>>>(x_l, x_p, W_node, xl0, xp0);
  k_vvec<<<2, 256, 0, stream>>>(W_el, W1, vvec);
  k_w2t<<<256, 256, 0, stream>>>(W2, w2t);
  k_wmt<<<64, 256, 0, stream>>>(Wm, wmt);
  k_wcat<<<768, 256, 0, stream>>>(Ws, Wn, wcat);
  k_w1t<<<512, 256, 0, stream>>>(W1, w1t);
  k_lut<<<12288, 256, 0, stream>>>(Wb, bb, lut);

  k_count<<<1954, 256, 0, stream>>>(esrc, edst, cntL, cntP);
  k_chunkscan<<<49, 256, 0, stream>>>(cntL, rowptrL, bsumL, NLn);
  k_chunkscan<<<147, 256, 0, stream>>>(cntP, rowptrP, bsumP, NPn);
  k_scanb<<<1, 256, 0, stream>>>(bsumL, 49);
  k_scanb<<<1, 256, 0, stream>>>(bsumP, 147);
  k_addoff<<<196, 256, 0, stream>>>(rowptrL, cursorL, bsumL, NLn);
  k_addoff<<<586, 256, 0, stream>>>(rowptrP, cursorP, bsumP, NPn);
  k_place<<<1954, 256, 0, stream>>>(esrc, edst, ea, lbatch, cursorL, cursorP,
                                    edgeL, idxL, idxP);

  unsigned short *xlc = xl0, *xln = xl1, *xpc = xp0, *xpn = xp1;
  for (int l = 0; l < 3; ++l){
    int ilp = 2*l, ipl = 2*l + 1;
    k_conv2<<<NBP + NBL, 256, 0, stream>>>(
        xpc, xlc, xpn, xln, xp_s, xl_s,
        rowptrP, idxP, rowptrL, idxL,
        lut + (size_t)ilp*524288, wcat + ilp*32768, bconv + ilp*128,
        lut + (size_t)ipl*524288, wcat + ipl*32768, bconv + ipl*128);
    unsigned short* t;
    t = xlc; xlc = xln; xln = t;
    t = xpc; xpc = xpn; xpn = t;
  }

  // b1 folded into h_l (ligand part); protein part no bias
  k_hproj2<<<NBL + NBP, 256, 0, stream>>>(xl_s, xp_s, w1t, b1, h_l, h_p);

  k_readout3<<<En/32, 256, 0, stream>>>(h_l, h_p, edgeL, vvec,
                                        w2t, b2, wmt, bm, out, mmax);
  k_final<<<128, 256, 0, stream>>>(mmax, out);
}

// Round 11
// 1808.417 us; speedup vs baseline: 1.6143x; 1.0127x over previous
//
#include <hip/hip_runtime.h>
#include <hip/hip_bf16.h>

// HeteroNet on MI355X — round 11.
// R10: LUT worked (2217->1831); readout 354 #1; conv2 ~260x3; ~340us launch gaps
// across 23 launches. R11: (a) k_prep mega-kernel + merged scan kernels: 23->12
// launches; (b) conv2 row-pair interleaved edge loops (4 loads in flight at
// deg~3, wave-uniform bounds); (c) layer-0 writes xsum directly (no 51MB zero).

#define NLn 50000
#define NPn 150000
#define En  500000
#define NBL 1563   // ceil(NLn/32)
#define NBP 4688   // ceil(NPn/32)

typedef __attribute__((ext_vector_type(8))) short short8;
typedef __attribute__((ext_vector_type(4))) float float4v;

__device__ __forceinline__ float bf2f(unsigned short u){ return __uint_as_float(((unsigned)u) << 16); }
__device__ __forceinline__ float bflo(unsigned u){ return __uint_as_float(u << 16); }
__device__ __forceinline__ float bfhi(unsigned u){ return __uint_as_float(u & 0xffff0000u); }
__device__ __forceinline__ unsigned short f2bf(float f){
  __hip_bfloat16 h = __float2bfloat16(f);
  return *reinterpret_cast<unsigned short*>(&h);
}
// order-preserving float->uint; enc(v)>0 for all finite v, so 0 == "empty segment"
__device__ __forceinline__ unsigned encf(float f){
  unsigned u = __float_as_uint(f);
  return (u & 0x80000000u) ? ~u : (u | 0x80000000u);
}
__device__ __forceinline__ float tanh_fast(float x){
  return 1.f - 2.f/(__expf(2.f*x) + 1.f);
}

// ---- k_prep: zeros + embed + weight transforms + LUT, one launch ----
// block ranges: [0,196) zero cnt | [196,324) zero mmax | [324,580) zero out |
// [580,100580) embed | [100580,100582) vvec | [,100838) w2t | [,100902) wmt |
// [,101670) wcat | [,102182) w1t | [,114470) lut
__global__ __launch_bounds__(256) void k_prep(
    unsigned* __restrict__ cntz, unsigned* __restrict__ mmaxz, unsigned* __restrict__ outz,
    const float* __restrict__ Xl, const float* __restrict__ Xp,
    const float* __restrict__ Wnode,
    unsigned short* __restrict__ xl0, unsigned short* __restrict__ xp0,
    const float* __restrict__ Wel, const float* __restrict__ W1, float* __restrict__ vvec,
    const float* __restrict__ W2, unsigned short* __restrict__ w2t,
    const float* __restrict__ Wm, unsigned short* __restrict__ wmt,
    const float* __restrict__ Ws, const float* __restrict__ Wn,
    unsigned short* __restrict__ wcat, unsigned short* __restrict__ w1t,
    const float* __restrict__ Wb, const float* __restrict__ bb,
    unsigned short* __restrict__ lut){
  int b = blockIdx.x, tid = threadIdx.x;
  if (b < 196){
    for (long i = (long)b*256 + tid; i < 200000; i += 196*256) cntz[i] = 0u;
  } else if (b < 324){
    mmaxz[(b-196)*256 + tid] = 0u;
  } else if (b < 580){
    outz[(b-324)*256 + tid] = 0u;
  } else if (b < 100580){
    int lb = b - 580;
    bool isL = lb < 25000;
    const float* X = isL ? Xl : Xp;
    unsigned short* out = isL ? xl0 : xp0;
    int gid = (isL ? lb : lb - 25000)*256 + tid;
    int n = gid >> 7, c = gid & 127;
    const float* xr = X + (size_t)n*44;
    float acc = 0.f;
    #pragma unroll
    for (int k=0;k<44;k++) acc += xr[k]*Wnode[k*128+c];
    out[(size_t)n*128 + c] = f2bf(acc);
  } else if (b < 100582){
    int j = (b-100580)*256 + tid;
    float s = 0.f;
    #pragma unroll
    for (int r=0;r<8;r++) s += Wel[r]*W1[(256+r)*512 + j];
    vvec[j] = s;
  } else if (b < 100838){
    int gid = (b-100582)*256 + tid;                    // 65536
    int n = gid >> 9, k = gid & 511;
    w2t[n*512 + k] = f2bf(W2[k*128 + n]);
  } else if (b < 100902){
    int gid = (b-100838)*256 + tid;                    // 16384
    int n = gid >> 7, k = gid & 127;
    wmt[n*128 + k] = f2bf(Wm[k*128 + n]);
  } else if (b < 101670){
    int gid = (b-100902)*256 + tid;                    // 196608
    int i = gid >> 15, rem = gid & 32767;
    int n = rem >> 8, k = rem & 255;
    float v = (k < 128) ? Ws[i*16384 + k*128 + n] : Wn[i*16384 + (k-128)*128 + n];
    wcat[gid] = f2bf(v);
  } else if (b < 102182){
    int gid = (b-101670)*256 + tid;                    // 131072
    int part = gid >> 16, rem = gid & 65535;
    int n = rem >> 7, k = rem & 127;
    w1t[gid] = f2bf(W1[(part*128 + k)*512 + n]);
  } else {
    int gid = (b-102182)*256 + tid;                    // 3145728
    int c = gid & 127, bin = (gid >> 7) & 4095, i = gid >> 19;
    float d = ((float)bin + 0.5f) * 0.001220703125f;   // *5/4096
    float s = bb[i*128 + c];
    #pragma unroll
    for (int j=0;j<8;j++){
      float a = (d - 0.7142857143f*(float)j) * 1.6f;
      s += __expf(-a*a) * Wb[i*1024 + j*128 + c];
    }
    lut[gid] = f2bf(s / (1.f + __expf(-s)));
  }
}

// ---- CSR construction ----
__global__ __launch_bounds__(256) void k_count(const int* __restrict__ esrc,
    const int* __restrict__ edst, unsigned* __restrict__ cntL, unsigned* __restrict__ cntP){
  int e = blockIdx.x*256 + threadIdx.x;
  if (e >= En) return;
  atomicAdd(&cntL[esrc[e]], 1u);
  atomicAdd(&cntP[edst[e]], 1u);
}
// merged chunkscan: blocks [0,49) ligand; [49,196) protein
__global__ __launch_bounds__(256) void k_cs2(const unsigned* __restrict__ cntL,
    unsigned* __restrict__ rowptrL, unsigned* __restrict__ bsumL,
    const unsigned* __restrict__ cntP, unsigned* __restrict__ rowptrP,
    unsigned* __restrict__ bsumP){
  bool isL = blockIdx.x < 49;
  const unsigned* cnt = isL ? cntL : cntP;
  unsigned* rowptr = isL ? rowptrL : rowptrP;
  unsigned* bsum = isL ? bsumL : bsumP;
  int n = isL ? NLn : NPn;
  int lb = isL ? blockIdx.x : blockIdx.x - 49;
  __shared__ unsigned ts[256];
  int tid = threadIdx.x;
  int base = lb*1024 + tid*4;
  unsigned v[4], run = 0;
  #pragma unroll
  for (int j=0;j<4;j++){ v[j] = run; run += (base+j < n) ? cnt[base+j] : 0u; }
  ts[tid] = run; __syncthreads();
  for (int off=1; off<256; off<<=1){
    unsigned t = (tid>=off) ? ts[tid-off] : 0u; __syncthreads();
    ts[tid] += t; __syncthreads();
  }
  unsigned excl = ts[tid] - run;
  #pragma unroll
  for (int j=0;j<4;j++) if (base+j < n) rowptr[base+j] = excl + v[j];
  if (tid == 255) bsum[lb] = ts[255];
}
// merged block-sum scan: block 0 ligand (49), block 1 protein (147)
__global__ void k_sb2(unsigned* __restrict__ bsumL, unsigned* __restrict__ bsumP){
  unsigned* bsum = blockIdx.x ? bsumP : bsumL;
  int nc = blockIdx.x ? 147 : 49;
  __shared__ unsigned ts[256];
  int tid = threadIdx.x;
  unsigned x = (tid < nc) ? bsum[tid] : 0u;
  ts[tid] = x; __syncthreads();
  for (int off=1; off<256; off<<=1){
    unsigned t = (tid>=off) ? ts[tid-off] : 0u; __syncthreads();
    ts[tid] += t; __syncthreads();
  }
  if (tid < nc) bsum[tid] = ts[tid] - x;
}
// merged addoff: blocks [0,196) ligand; [196,782) protein
__global__ __launch_bounds__(256) void k_ao2(
    unsigned* __restrict__ rowptrL, unsigned* __restrict__ cursorL,
    const unsigned* __restrict__ bsumL,
    unsigned* __restrict__ rowptrP, unsigned* __restrict__ cursorP,
    const unsigned* __restrict__ bsumP){
  bool isL = blockIdx.x < 196;
  unsigned* rowptr = isL ? rowptrL : rowptrP;
  unsigned* cursor = isL ? cursorL : cursorP;
  const unsigned* bsum = isL ? bsumL : bsumP;
  int n = isL ? NLn : NPn;
  int i = (isL ? blockIdx.x : blockIdx.x - 196)*256 + threadIdx.x;
  if (i < n){
    unsigned r = rowptr[i] + bsum[i>>10];
    rowptr[i] = r; cursor[i] = r;
  }
  if (i == 0) rowptr[n] = En;
}
// place edges into both CSR orders; idx packed with LUT bin (idx | bin<<18)
__global__ __launch_bounds__(256) void k_place(const int* __restrict__ esrc,
    const int* __restrict__ edst, const float* __restrict__ ea,
    const int* __restrict__ lbatch, unsigned* __restrict__ curL,
    unsigned* __restrict__ curP, uint4* __restrict__ edgeL,
    int* __restrict__ idxL, int* __restrict__ idxP){
  int e = blockIdx.x*256 + threadIdx.x;
  if (e >= En) return;
  int s = esrc[e], d = edst[e];
  float dd = ea[e];
  int bin = (int)(dd * 819.2f);
  bin = (bin < 0) ? 0 : ((bin > 4095) ? 4095 : bin);
  unsigned pl = atomicAdd(&curL[s], 1u);
  uint4 er; er.x = (unsigned)s; er.y = (unsigned)d;
  er.z = __float_as_uint(dd); er.w = (unsigned)lbatch[s];
  edgeL[pl] = er;
  idxL[pl] = d | (bin << 18);
  unsigned pp = atomicAdd(&curP[d], 1u);
  idxP[pp] = s | (bin << 18);
}

// ---- fused dual-direction conv with silu-LUT, row-pair interleaved edge loops ----
#define EDGE_CAP 1024
__global__ __launch_bounds__(256) void k_conv2(
    const unsigned short* __restrict__ xp_in, const unsigned short* __restrict__ xl_in,
    unsigned short* __restrict__ xp_out, unsigned short* __restrict__ xl_out,
    unsigned short* __restrict__ xp_sum, unsigned short* __restrict__ xl_sum,
    const unsigned* __restrict__ rowptrP, const int* __restrict__ idxP,
    const unsigned* __restrict__ rowptrL, const int* __restrict__ idxL,
    const unsigned short* __restrict__ lut_lp,
    const unsigned short* __restrict__ wcat_lp, const float* __restrict__ bias_lp,
    const unsigned short* __restrict__ lut_pl,
    const unsigned short* __restrict__ wcat_pl, const float* __restrict__ bias_pl,
    int first){
  __shared__ unsigned short ab[32][264];   // [m][k]: k<128 x_dst, k>=128 agg (bf16)
  __shared__ unsigned short ob[32][136];   // epilogue bf16
  __shared__ int snb[EDGE_CAP];
  __shared__ unsigned rps[33];
  int tid = threadIdx.x, c = tid & 127, hh = tid >> 7;
  bool isP = blockIdx.x < NBP;
  const unsigned short* xdst_in = isP ? xp_in : xl_in;
  const unsigned short* xsrc_in = isP ? xl_in : xp_in;
  unsigned short* xout = isP ? xp_out : xl_out;
  unsigned short* xsum = isP ? xp_sum : xl_sum;
  const unsigned* rowptr = isP ? rowptrP : rowptrL;
  const int* eidx = isP ? idxP : idxL;
  const unsigned short* lut_i = isP ? lut_lp : lut_pl;
  const unsigned short* wcat = isP ? wcat_lp : wcat_pl;
  const float* bias = isP ? bias_lp : bias_pl;
  int ndst = isP ? NPn : NLn;
  int n0 = (isP ? blockIdx.x : (blockIdx.x - NBP)) * 32;

  if (tid < 33){
    int idx = n0 + tid; if (idx > ndst) idx = ndst;
    rps[tid] = rowptr[idx];
  }
  __syncthreads();
  int r00 = (int)rps[0], rEnd = (int)rps[32];
  int eblk = rEnd - r00;
  bool fits = (eblk <= EDGE_CAP);
  if (fits){
    for (int p = tid; p < eblk; p += 256) snb[p] = eidx[r00 + p];
  }
  __syncthreads();

  const unsigned short* lutc = lut_i + c;
  const unsigned short* xc = xsrc_in + c;
  for (int mp = 0; mp < 8; mp++){
    int mA = hh*16 + mp*2, mB = mA + 1;
    int nA = n0 + mA, nB = n0 + mB;
    ab[mA][c] = (nA < ndst) ? xdst_in[(size_t)nA*128 + c] : (unsigned short)0;
    ab[mB][c] = (nB < ndst) ? xdst_in[(size_t)nB*128 + c] : (unsigned short)0;
    int r0A = (int)rps[mA], r1A = (int)rps[mA+1];
    int r0B = (int)rps[mB], r1B = (int)rps[mB+1];
    if (nA >= ndst) r1A = r0A;
    if (nB >= ndst) r1B = r0B;
    float aA0=0.f, aA1=0.f, aB0=0.f, aB1=0.f;
    int pA = r0A, pB = r0B;
    int dA = r1A - pA, dB = r1B - pB;
    int nj = (dA < dB) ? dA : dB;
    for (int j=0;j<nj;j++){
      int vA = fits ? snb[pA - r00] : eidx[pA];
      int vB = fits ? snb[pB - r00] : eidx[pB];
      aA0 += bf2f(lutc[(size_t)((unsigned)vA >> 18)*128]) * bf2f(xc[(size_t)(vA & 0x3FFFF)*128]);
      aB0 += bf2f(lutc[(size_t)((unsigned)vB >> 18)*128]) * bf2f(xc[(size_t)(vB & 0x3FFFF)*128]);
      pA++; pB++;
    }
    for (; pA + 1 < r1A; pA += 2){
      int v0 = fits ? snb[pA - r00] : eidx[pA];
      int v1 = fits ? snb[pA+1 - r00] : eidx[pA+1];
      aA0 += bf2f(lutc[(size_t)((unsigned)v0 >> 18)*128]) * bf2f(xc[(size_t)(v0 & 0x3FFFF)*128]);
      aA1 += bf2f(lutc[(size_t)((unsigned)v1 >> 18)*128]) * bf2f(xc[(size_t)(v1 & 0x3FFFF)*128]);
    }
    if (pA < r1A){
      int v0 = fits ? snb[pA - r00] : eidx[pA];
      aA0 += bf2f(lutc[(size_t)((unsigned)v0 >> 18)*128]) * bf2f(xc[(size_t)(v0 & 0x3FFFF)*128]);
    }
    for (; pB + 1 < r1B; pB += 2){
      int v0 = fits ? snb[pB - r00] : eidx[pB];
      int v1 = fits ? snb[pB+1 - r00] : eidx[pB+1];
      aB0 += bf2f(lutc[(size_t)((unsigned)v0 >> 18)*128]) * bf2f(xc[(size_t)(v0 & 0x3FFFF)*128]);
      aB1 += bf2f(lutc[(size_t)((unsigned)v1 >> 18)*128]) * bf2f(xc[(size_t)(v1 & 0x3FFFF)*128]);
    }
    if (pB < r1B){
      int v0 = fits ? snb[pB - r00] : eidx[pB];
      aB0 += bf2f(lutc[(size_t)((unsigned)v0 >> 18)*128]) * bf2f(xc[(size_t)(v0 & 0x3FFFF)*128]);
    }
    int dgA = r1A - r0A, dgB = r1B - r0B;
    ab[mA][128 + c] = f2bf((aA0+aA1) * (1.f/(float)(dgA > 1 ? dgA : 1)));
    ab[mB][128 + c] = f2bf((aB0+aB1) * (1.f/(float)(dgB > 1 ? dgB : 1)));
  }
  __syncthreads();

  int wave = tid >> 6, lane = tid & 63, quad = lane >> 4, l15 = lane & 15;
  int mt = wave & 1, nh = wave >> 1;
  int arow = mt*16 + l15;
  float4v acc[4] = {{0,0,0,0},{0,0,0,0},{0,0,0,0},{0,0,0,0}};
  for (int k0 = 0; k0 < 256; k0 += 32){
    short8 A = *(const short8*)&ab[arow][k0 + quad*8];
    #pragma unroll
    for (int nt=0;nt<4;nt++){
      short8 B = *(const short8*)&wcat[(size_t)(nh*64 + nt*16 + l15)*256 + k0 + quad*8];
      acc[nt] = __builtin_amdgcn_mfma_f32_16x16x32_bf16(A, B, acc[nt], 0, 0, 0);
    }
  }
  #pragma unroll
  for (int nt=0;nt<4;nt++){
    int col = nh*64 + nt*16 + l15;
    float bc = bias[col];
    #pragma unroll
    for (int r=0;r<4;r++){
      int row = mt*16 + quad*4 + r;
      float v = acc[nt][r] + bc;
      ob[row][col] = f2bf((v > 0.f) ? v : 0.01f*v);    // leaky_relu
    }
  }
  __syncthreads();
  for (int m = hh*16; m < hh*16+16; m++){
    int n = n0 + m;
    if (n < ndst){
      unsigned short vb = ob[m][c];
      size_t off = (size_t)n*128 + c;
      xout[off] = vb;
      xsum[off] = first ? vb : f2bf(bf2f(xsum[off]) + bf2f(vb));
    }
  }
}

// ---- merged MFMA hproj: blocks [0,NBL): ligand (+b1); [NBL,NBL+NBP): protein
__global__ __launch_bounds__(256) void k_hproj2(
    const unsigned short* __restrict__ xl_s, const unsigned short* __restrict__ xp_s,
    const unsigned short* __restrict__ w1t, const float* __restrict__ b1,
    unsigned* __restrict__ h_l, unsigned* __restrict__ h_p){
  __shared__ unsigned short hb[32][528];
  bool isL = blockIdx.x < NBL;
  const unsigned short* xs = isL ? xl_s : xp_s;
  const unsigned short* wt = isL ? w1t : w1t + 65536;
  unsigned* hout = isL ? h_l : h_p;
  int nn = isL ? NLn : NPn;
  int n0 = (isL ? blockIdx.x : blockIdx.x - NBL)*32;
  int tid = threadIdx.x;
  int wave = tid >> 6, lane = tid & 63, quad = lane >> 4, l15 = lane & 15;
  int mt = wave & 1, nh = wave >> 1;
  int an = n0 + mt*16 + l15; if (an >= nn) an = nn - 1;
  const unsigned short* aptr = xs + (size_t)an*128;
  float4v acc[16];
  #pragma unroll
  for (int i=0;i<16;i++) acc[i] = (float4v){0,0,0,0};
  for (int k0 = 0; k0 < 128; k0 += 32){
    short8 A = *(const short8*)&aptr[k0 + quad*8];
    #pragma unroll
    for (int nt=0;nt<16;nt++){
      short8 B = *(const short8*)&wt[(size_t)(nh*256 + nt*16 + l15)*128 + k0 + quad*8];
      acc[nt] = __builtin_amdgcn_mfma_f32_16x16x32_bf16(A, B, acc[nt], 0, 0, 0);
    }
  }
  #pragma unroll
  for (int nt=0;nt<16;nt++){
    int col = nh*256 + nt*16 + l15;
    float bv = isL ? b1[col] : 0.f;
    #pragma unroll
    for (int r=0;r<4;r++) hb[mt*16 + quad*4 + r][col] = f2bf(acc[nt][r] + bv);
  }
  __syncthreads();
  for (int m=0;m<32;m++){
    int n = n0 + m;
    if (n < nn){
      unsigned pack = (unsigned)hb[m][2*tid] | ((unsigned)hb[m][2*tid+1] << 16);
      hout[(size_t)n*256 + tid] = pack;
    }
  }
}

// ---- readout v3: 32 edges/block; coalesced LDS staging; (M32,N32) wave tiles;
//      m in registers; shuffle-butterfly flush. b1 pre-folded into h_l.
__global__ __launch_bounds__(256, 4) void k_readout3(
    const unsigned* __restrict__ hl, const unsigned* __restrict__ hp,
    const uint4* __restrict__ edgeL, const float* __restrict__ vvec,
    const unsigned short* __restrict__ w2t, const float* __restrict__ b2,
    const unsigned short* __restrict__ wmt, const float* __restrict__ bm,
    float* __restrict__ outw, unsigned* __restrict__ mmax){
  __shared__ __align__(16) char smem[33280];
  unsigned short (*hbuf)[520] = (unsigned short(*)[520])smem;   // dead after GEMM1
  unsigned short (*msb)[136]  = (unsigned short(*)[136])smem;   // aliases hbuf
  __shared__ int sidx[32], didx[32], bsh[32];
  __shared__ float dsts[32];
  int tid = threadIdx.x;
  int e0 = blockIdx.x*32;
  if (tid < 32){
    uint4 er = edgeL[e0 + tid];
    sidx[tid] = (int)er.x; didx[tid] = (int)er.y;
    dsts[tid] = __uint_as_float(er.z); bsh[tid] = (int)er.w;
  }
  __syncthreads();
  int j2 = tid*2;
  float2 vv = *(const float2*)&vvec[j2];
  #pragma unroll 8
  for (int i=0;i<32;i++){
    unsigned ua = hl[(size_t)sidx[i]*256 + tid];
    unsigned ub = hp[(size_t)didx[i]*256 + tid];
    float dd = dsts[i];
    float hx = fmaxf(bflo(ua) + bflo(ub) + dd*vv.x, 0.f);
    float hy = fmaxf(bfhi(ua) + bfhi(ub) + dd*vv.y, 0.f);
    *(unsigned*)&hbuf[i][j2] = (unsigned)f2bf(hx) | ((unsigned)f2bf(hy) << 16);
  }
  __syncthreads();
  int wave = tid >> 6, lane = tid & 63, quad = lane >> 4, l15 = lane & 15;
  int ns = wave*32;            // each wave: M=32 (all edges), N-strip of 32

  // GEMM1: m[32,128] = h[32,512] @ W2^T + b2
  float4v acc[2][2] = {{{0,0,0,0},{0,0,0,0}},{{0,0,0,0},{0,0,0,0}}};
  for (int k0 = 0; k0 < 512; k0 += 32){
    short8 A0 = *(const short8*)&hbuf[l15][k0 + quad*8];
    short8 A1 = *(const short8*)&hbuf[16 + l15][k0 + quad*8];
    short8 B0 = *(const short8*)&w2t[(size_t)(ns + l15)*512 + k0 + quad*8];
    short8 B1 = *(const short8*)&w2t[(size_t)(ns + 16 + l15)*512 + k0 + quad*8];
    acc[0][0] = __builtin_amdgcn_mfma_f32_16x16x32_bf16(A0, B0, acc[0][0], 0, 0, 0);
    acc[0][1] = __builtin_amdgcn_mfma_f32_16x16x32_bf16(A0, B1, acc[0][1], 0, 0, 0);
    acc[1][0] = __builtin_amdgcn_mfma_f32_16x16x32_bf16(A1, B0, acc[1][0], 0, 0, 0);
    acc[1][1] = __builtin_amdgcn_mfma_f32_16x16x32_bf16(A1, B1, acc[1][1], 0, 0, 0);
  }
  __syncthreads();   // all waves done reading hbuf; msb may overwrite
  float mreg[2][2][4];
  float b2c0 = b2[ns + l15], b2c1 = b2[ns + 16 + l15];
  #pragma unroll
  for (int mt=0;mt<2;mt++){
    #pragma unroll
    for (int nt=0;nt<2;nt++){
      float b2c = nt ? b2c1 : b2c0;
      int col = ns + nt*16 + l15;
      #pragma unroll
      for (int r=0;r<4;r++){
        float mv = acc[mt][nt][r] + b2c;
        mreg[mt][nt][r] = mv;
        msb[mt*16 + quad*4 + r][col] = f2bf(mv);
      }
    }
  }
  __syncthreads();

  // GEMM2: t = tanh(m@Wm^T + bm); flush sum(t*m), max(m) per batch
  float4v acc2[2][2] = {{{0,0,0,0},{0,0,0,0}},{{0,0,0,0},{0,0,0,0}}};
  for (int k0 = 0; k0 < 128; k0 += 32){
    short8 A0 = *(const short8*)&msb[l15][k0 + quad*8];
    short8 A1 = *(const short8*)&msb[16 + l15][k0 + quad*8];
    short8 B0 = *(const short8*)&wmt[(size_t)(ns + l15)*128 + k0 + quad*8];
    short8 B1 = *(const short8*)&wmt[(size_t)(ns + 16 + l15)*128 + k0 + quad*8];
    acc2[0][0] = __builtin_amdgcn_mfma_f32_16x16x32_bf16(A0, B0, acc2[0][0], 0, 0, 0);
    acc2[0][1] = __builtin_amdgcn_mfma_f32_16x16x32_bf16(A0, B1, acc2[0][1], 0, 0, 0);
    acc2[1][0] = __builtin_amdgcn_mfma_f32_16x16x32_bf16(A1, B0, acc2[1][0], 0, 0, 0);
    acc2[1][1] = __builtin_amdgcn_mfma_f32_16x16x32_bf16(A1, B1, acc2[1][1], 0, 0, 0);
  }
  float bm0 = bm[ns + l15], bm1 = bm[ns + 16 + l15];
  bool uni = (bsh[0] == bsh[31]);
  int b0 = bsh[0];
  #pragma unroll
  for (int nt=0;nt<2;nt++){
    int col = ns + nt*16 + l15;
    float bmc = nt ? bm1 : bm0;
    if (uni){
      float s = 0.f, mx = -3.402823466e38f;
      #pragma unroll
      for (int mt=0;mt<2;mt++){
        #pragma unroll
        for (int r=0;r<4;r++){
          float mv = mreg[mt][nt][r];
          float t = tanh_fast(acc2[mt][nt][r] + bmc);
          s += t*mv; mx = fmaxf(mx, mv);
        }
      }
      s += __shfl_xor(s, 16); s += __shfl_xor(s, 32);
      mx = fmaxf(mx, __shfl_xor(mx, 16)); mx = fmaxf(mx, __shfl_xor(mx, 32));
      if (quad == 0){
        atomicAdd(&outw[b0*256 + col], s);
        atomicMax(&mmax[b0*128 + col], encf(mx));
      }
    } else {
      #pragma unroll
      for (int mt=0;mt<2;mt++){
        #pragma unroll
        for (int r=0;r<4;r++){
          int row = mt*16 + quad*4 + r;
          int b = bsh[row];
          float mv = mreg[mt][nt][r];
          float t = tanh_fast(acc2[mt][nt][r] + bmc);
          atomicAdd(&outw[b*256 + col], t*mv);
          atomicMax(&mmax[b*128 + col], encf(mv));
        }
      }
    }
  }
}

__global__ __launch_bounds__(256) void k_final(const unsigned* __restrict__ mmax,
    float* __restrict__ out){
  int gid = blockIdx.x*256 + threadIdx.x;   // 32768 = 256*128
  unsigned enc = mmax[gid];
  float v;
  if (enc == 0u) v = 0.f;
  else if (enc & 0x80000000u) v = __uint_as_float(enc & 0x7FFFFFFFu);
  else v = __uint_as_float(~enc);
  int g = gid >> 7, cc = gid & 127;
  out[g*256 + 128 + cc] = v;
}

extern "C" void kernel_launch(void* const* d_in, const int* in_sizes, int n_in,
                              void* d_out, int out_size, void* d_ws, size_t ws_size,
                              hipStream_t stream) {
  const float* x_l    = (const float*)d_in[0];
  const float* x_p    = (const float*)d_in[1];
  const float* ea     = (const float*)d_in[2];
  const int*   esrc   = (const int*)d_in[3];
  const int*   edst   = (const int*)d_in[4];
  const int*   lbatch = (const int*)d_in[5];
  const float* W_node = (const float*)d_in[6];
  const float* W_el   = (const float*)d_in[7];
  const float* Wb     = (const float*)d_in[8];
  const float* bb     = (const float*)d_in[9];
  const float* Wn     = (const float*)d_in[10];
  const float* Ws     = (const float*)d_in[11];
  const float* bconv  = (const float*)d_in[12];
  const float* W1     = (const float*)d_in[13];
  const float* b1     = (const float*)d_in[14];
  const float* W2     = (const float*)d_in[15];
  const float* b2     = (const float*)d_in[16];
  const float* Wm     = (const float*)d_in[17];
  const float* bm     = (const float*)d_in[18];

  // ---- workspace layout (decimal offsets), peak 267,354,496 B ----
  char* w = (char*)d_ws;
  unsigned short* xl0 = (unsigned short*)(w + 0);
  unsigned short* xl1 = (unsigned short*)(w + 12800000);
  unsigned short* xp0 = (unsigned short*)(w + 25600000);
  unsigned short* xp1 = (unsigned short*)(w + 64000000);
  int*      idxP  = (int*)(w + 102400000);
  int*      idxL  = (int*)(w + 104400000);
  unsigned short* lut = (unsigned short*)(w + 106400000);   // 6.29e6 B
  unsigned* h_l   = (unsigned*)(w + 0);
  unsigned* h_p   = (unsigned*)(w + 51200000);
  unsigned short* xl_s = (unsigned short*)(w + 204800000);
  unsigned short* xp_s = (unsigned short*)(w + 217600000);
  unsigned short* wcat = (unsigned short*)(w + 256000000);
  unsigned short* w1t  = (unsigned short*)(w + 256393216);
  unsigned short* w2t  = (unsigned short*)(w + 256655360);
  unsigned short* wmt  = (unsigned short*)(w + 256786432);
  float*    vvec  = (float*)(w + 256819200);
  unsigned* mmax  = (unsigned*)(w + 256821248);
  unsigned* bsumL = (unsigned*)(w + 256952320);
  unsigned* bsumP = (unsigned*)(w + 256953344);
  unsigned* rowptrL = (unsigned*)(w + 256954368);
  unsigned* cursorL = (unsigned*)(w + 257154432);
  unsigned* rowptrP = (unsigned*)(w + 257354432);
  unsigned* cursorP = (unsigned*)(w + 257954496);
  unsigned* cntL    = (unsigned*)(w + 258554496);
  unsigned* cntP    = (unsigned*)(w + 258754496);
  uint4*    edgeL   = (uint4*)(w + 259354496);   // {src, dst, bits(d), batch}

  float* out = (float*)d_out;

  k_prep<<<114470, 256, 0, stream>>>(
      (unsigned*)(w + 258554496), mmax, (unsigned*)d_out,
      x_l, x_p, W_node, xl0, xp0,
      W_el, W1, vvec, W2, w2t, Wm, wmt, Ws, Wn, wcat, w1t, Wb, bb, lut);

  k_count<<<1954, 256, 0, stream>>>(esrc, edst, cntL, cntP);
  k_cs2<<<196, 256, 0, stream>>>(cntL, rowptrL, bsumL, cntP, rowptrP, bsumP);
  k_sb2<<<2, 256, 0, stream>>>(bsumL, bsumP);
  k_ao2<<<782, 256, 0, stream>>>(rowptrL, cursorL, bsumL, rowptrP, cursorP, bsumP);
  k_place<<<1954, 256, 0, stream>>>(esrc, edst, ea, lbatch, cursorL, cursorP,
                                    edgeL, idxL, idxP);

  unsigned short *xlc = xl0, *xln = xl1, *xpc = xp0, *xpn = xp1;
  for (int l = 0; l < 3; ++l){
    int ilp = 2*l, ipl = 2*l + 1;
    k_conv2<<<NBP + NBL, 256, 0, stream>>>(
        xpc, xlc, xpn, xln, xp_s, xl_s,
        rowptrP, idxP, rowptrL, idxL,
        lut + (size_t)ilp*524288, wcat + ilp*32768, bconv + ilp*128,
        lut + (size_t)ipl*524288, wcat + ipl*32768, bconv + ipl*128,
        (l == 0) ? 1 : 0);
    unsigned short* t;
    t = xlc; xlc = xln; xln = t;
    t = xpc; xpc = xpn; xpn = t;
  }

  // b1 folded into h_l (ligand part); protein part no bias
  k_hproj2<<<NBL + NBP, 256, 0, stream>>>(xl_s, xp_s, w1t, b1, h_l, h_p);

  k_readout3<<<En/32, 256, 0, stream>>>(h_l, h_p, edgeL, vvec,
                                        w2t, b2, wmt, bm, out, mmax);
  k_final<<<128, 256, 0, stream>>>(mmax, out);
}

// Round 12
// 1782.890 us; speedup vs baseline: 1.6374x; 1.0143x over previous
//
#include <hip/hip_runtime.h>
#include <hip/hip_bf16.h>

// HeteroNet on MI355X — round 12.
// R11: +23us only; readout occupancy hard-capped by LDS (33.8KB -> 4 blk/CU);
// conv2 row-pair interleave suspected regression. R12:
//  (a) readout4: LDS = exactly 32768B (chunk+xor-swizzle hbuf layout, metadata
//      in wave regs via shfl) -> 5 blk/CU (163840B = exactly 160KiB);
//  (b) conv2 inner loop reverted to R10 unroll-4 (known-good).

#define NLn 50000
#define NPn 150000
#define En  500000
#define NBL 1563   // ceil(NLn/32)
#define NBP 4688   // ceil(NPn/32)

typedef __attribute__((ext_vector_type(8))) short short8;
typedef __attribute__((ext_vector_type(4))) float float4v;

__device__ __forceinline__ float bf2f(unsigned short u){ return __uint_as_float(((unsigned)u) << 16); }
__device__ __forceinline__ float bflo(unsigned u){ return __uint_as_float(u << 16); }
__device__ __forceinline__ float bfhi(unsigned u){ return __uint_as_float(u & 0xffff0000u); }
__device__ __forceinline__ unsigned short f2bf(float f){
  __hip_bfloat16 h = __float2bfloat16(f);
  return *reinterpret_cast<unsigned short*>(&h);
}
// order-preserving float->uint; enc(v)>0 for all finite v, so 0 == "empty segment"
__device__ __forceinline__ unsigned encf(float f){
  unsigned u = __float_as_uint(f);
  return (u & 0x80000000u) ? ~u : (u | 0x80000000u);
}
__device__ __forceinline__ float tanh_fast(float x){
  return 1.f - 2.f/(__expf(2.f*x) + 1.f);
}

// ---- k_prep: zeros + embed + weight transforms + LUT, one launch ----
__global__ __launch_bounds__(256) void k_prep(
    unsigned* __restrict__ cntz, unsigned* __restrict__ mmaxz, unsigned* __restrict__ outz,
    const float* __restrict__ Xl, const float* __restrict__ Xp,
    const float* __restrict__ Wnode,
    unsigned short* __restrict__ xl0, unsigned short* __restrict__ xp0,
    const float* __restrict__ Wel, const float* __restrict__ W1, float* __restrict__ vvec,
    const float* __restrict__ W2, unsigned short* __restrict__ w2t,
    const float* __restrict__ Wm, unsigned short* __restrict__ wmt,
    const float* __restrict__ Ws, const float* __restrict__ Wn,
    unsigned short* __restrict__ wcat, unsigned short* __restrict__ w1t,
    const float* __restrict__ Wb, const float* __restrict__ bb,
    unsigned short* __restrict__ lut){
  int b = blockIdx.x, tid = threadIdx.x;
  if (b < 196){
    for (long i = (long)b*256 + tid; i < 200000; i += 196*256) cntz[i] = 0u;
  } else if (b < 324){
    mmaxz[(b-196)*256 + tid] = 0u;
  } else if (b < 580){
    outz[(b-324)*256 + tid] = 0u;
  } else if (b < 100580){
    int lb = b - 580;
    bool isL = lb < 25000;
    const float* X = isL ? Xl : Xp;
    unsigned short* out = isL ? xl0 : xp0;
    int gid = (isL ? lb : lb - 25000)*256 + tid;
    int n = gid >> 7, c = gid & 127;
    const float* xr = X + (size_t)n*44;
    float acc = 0.f;
    #pragma unroll
    for (int k=0;k<44;k++) acc += xr[k]*Wnode[k*128+c];
    out[(size_t)n*128 + c] = f2bf(acc);
  } else if (b < 100582){
    int j = (b-100580)*256 + tid;
    float s = 0.f;
    #pragma unroll
    for (int r=0;r<8;r++) s += Wel[r]*W1[(256+r)*512 + j];
    vvec[j] = s;
  } else if (b < 100838){
    int gid = (b-100582)*256 + tid;                    // 65536
    int n = gid >> 9, k = gid & 511;
    w2t[n*512 + k] = f2bf(W2[k*128 + n]);
  } else if (b < 100902){
    int gid = (b-100838)*256 + tid;                    // 16384
    int n = gid >> 7, k = gid & 127;
    wmt[n*128 + k] = f2bf(Wm[k*128 + n]);
  } else if (b < 101670){
    int gid = (b-100902)*256 + tid;                    // 196608
    int i = gid >> 15, rem = gid & 32767;
    int n = rem >> 8, k = rem & 255;
    float v = (k < 128) ? Ws[i*16384 + k*128 + n] : Wn[i*16384 + (k-128)*128 + n];
    wcat[gid] = f2bf(v);
  } else if (b < 102182){
    int gid = (b-101670)*256 + tid;                    // 131072
    int part = gid >> 16, rem = gid & 65535;
    int n = rem >> 7, k = rem & 127;
    w1t[gid] = f2bf(W1[(part*128 + k)*512 + n]);
  } else {
    int gid = (b-102182)*256 + tid;                    // 3145728
    int c = gid & 127, bin = (gid >> 7) & 4095, i = gid >> 19;
    float d = ((float)bin + 0.5f) * 0.001220703125f;   // *5/4096
    float s = bb[i*128 + c];
    #pragma unroll
    for (int j=0;j<8;j++){
      float a = (d - 0.7142857143f*(float)j) * 1.6f;
      s += __expf(-a*a) * Wb[i*1024 + j*128 + c];
    }
    lut[gid] = f2bf(s / (1.f + __expf(-s)));
  }
}

// ---- CSR construction ----
__global__ __launch_bounds__(256) void k_count(const int* __restrict__ esrc,
    const int* __restrict__ edst, unsigned* __restrict__ cntL, unsigned* __restrict__ cntP){
  int e = blockIdx.x*256 + threadIdx.x;
  if (e >= En) return;
  atomicAdd(&cntL[esrc[e]], 1u);
  atomicAdd(&cntP[edst[e]], 1u);
}
__global__ __launch_bounds__(256) void k_cs2(const unsigned* __restrict__ cntL,
    unsigned* __restrict__ rowptrL, unsigned* __restrict__ bsumL,
    const unsigned* __restrict__ cntP, unsigned* __restrict__ rowptrP,
    unsigned* __restrict__ bsumP){
  bool isL = blockIdx.x < 49;
  const unsigned* cnt = isL ? cntL : cntP;
  unsigned* rowptr = isL ? rowptrL : rowptrP;
  unsigned* bsum = isL ? bsumL : bsumP;
  int n = isL ? NLn : NPn;
  int lb = isL ? blockIdx.x : blockIdx.x - 49;
  __shared__ unsigned ts[256];
  int tid = threadIdx.x;
  int base = lb*1024 + tid*4;
  unsigned v[4], run = 0;
  #pragma unroll
  for (int j=0;j<4;j++){ v[j] = run; run += (base+j < n) ? cnt[base+j] : 0u; }
  ts[tid] = run; __syncthreads();
  for (int off=1; off<256; off<<=1){
    unsigned t = (tid>=off) ? ts[tid-off] : 0u; __syncthreads();
    ts[tid] += t; __syncthreads();
  }
  unsigned excl = ts[tid] - run;
  #pragma unroll
  for (int j=0;j<4;j++) if (base+j < n) rowptr[base+j] = excl + v[j];
  if (tid == 255) bsum[lb] = ts[255];
}
__global__ void k_sb2(unsigned* __restrict__ bsumL, unsigned* __restrict__ bsumP){
  unsigned* bsum = blockIdx.x ? bsumP : bsumL;
  int nc = blockIdx.x ? 147 : 49;
  __shared__ unsigned ts[256];
  int tid = threadIdx.x;
  unsigned x = (tid < nc) ? bsum[tid] : 0u;
  ts[tid] = x; __syncthreads();
  for (int off=1; off<256; off<<=1){
    unsigned t = (tid>=off) ? ts[tid-off] : 0u; __syncthreads();
    ts[tid] += t; __syncthreads();
  }
  if (tid < nc) bsum[tid] = ts[tid] - x;
}
__global__ __launch_bounds__(256) void k_ao2(
    unsigned* __restrict__ rowptrL, unsigned* __restrict__ cursorL,
    const unsigned* __restrict__ bsumL,
    unsigned* __restrict__ rowptrP, unsigned* __restrict__ cursorP,
    const unsigned* __restrict__ bsumP){
  bool isL = blockIdx.x < 196;
  unsigned* rowptr = isL ? rowptrL : rowptrP;
  unsigned* cursor = isL ? cursorL : cursorP;
  const unsigned* bsum = isL ? bsumL : bsumP;
  int n = isL ? NLn : NPn;
  int i = (isL ? blockIdx.x : blockIdx.x - 196)*256 + threadIdx.x;
  if (i < n){
    unsigned r = rowptr[i] + bsum[i>>10];
    rowptr[i] = r; cursor[i] = r;
  }
  if (i == 0) rowptr[n] = En;
}
__global__ __launch_bounds__(256) void k_place(const int* __restrict__ esrc,
    const int* __restrict__ edst, const float* __restrict__ ea,
    const int* __restrict__ lbatch, unsigned* __restrict__ curL,
    unsigned* __restrict__ curP, uint4* __restrict__ edgeL,
    int* __restrict__ idxL, int* __restrict__ idxP){
  int e = blockIdx.x*256 + threadIdx.x;
  if (e >= En) return;
  int s = esrc[e], d = edst[e];
  float dd = ea[e];
  int bin = (int)(dd * 819.2f);
  bin = (bin < 0) ? 0 : ((bin > 4095) ? 4095 : bin);
  unsigned pl = atomicAdd(&curL[s], 1u);
  uint4 er; er.x = (unsigned)s; er.y = (unsigned)d;
  er.z = __float_as_uint(dd); er.w = (unsigned)lbatch[s];
  edgeL[pl] = er;
  idxL[pl] = d | (bin << 18);
  unsigned pp = atomicAdd(&curP[d], 1u);
  idxP[pp] = s | (bin << 18);
}

// ---- fused dual-direction conv with silu-LUT (R10 unroll-4 inner loop) ----
#define EDGE_CAP 1024
__global__ __launch_bounds__(256) void k_conv2(
    const unsigned short* __restrict__ xp_in, const unsigned short* __restrict__ xl_in,
    unsigned short* __restrict__ xp_out, unsigned short* __restrict__ xl_out,
    unsigned short* __restrict__ xp_sum, unsigned short* __restrict__ xl_sum,
    const unsigned* __restrict__ rowptrP, const int* __restrict__ idxP,
    const unsigned* __restrict__ rowptrL, const int* __restrict__ idxL,
    const unsigned short* __restrict__ lut_lp,
    const unsigned short* __restrict__ wcat_lp, const float* __restrict__ bias_lp,
    const unsigned short* __restrict__ lut_pl,
    const unsigned short* __restrict__ wcat_pl, const float* __restrict__ bias_pl,
    int first){
  __shared__ unsigned short ab[32][264];   // [m][k]: k<128 x_dst, k>=128 agg (bf16)
  __shared__ unsigned short ob[32][136];   // epilogue bf16
  __shared__ int snb[EDGE_CAP];
  __shared__ unsigned rps[33];
  int tid = threadIdx.x, c = tid & 127, hh = tid >> 7;
  bool isP = blockIdx.x < NBP;
  const unsigned short* xdst_in = isP ? xp_in : xl_in;
  const unsigned short* xsrc_in = isP ? xl_in : xp_in;
  unsigned short* xout = isP ? xp_out : xl_out;
  unsigned short* xsum = isP ? xp_sum : xl_sum;
  const unsigned* rowptr = isP ? rowptrP : rowptrL;
  const int* eidx = isP ? idxP : idxL;
  const unsigned short* lut_i = isP ? lut_lp : lut_pl;
  const unsigned short* wcat = isP ? wcat_lp : wcat_pl;
  const float* bias = isP ? bias_lp : bias_pl;
  int ndst = isP ? NPn : NLn;
  int n0 = (isP ? blockIdx.x : (blockIdx.x - NBP)) * 32;

  if (tid < 33){
    int idx = n0 + tid; if (idx > ndst) idx = ndst;
    rps[tid] = rowptr[idx];
  }
  __syncthreads();
  int r00 = (int)rps[0], rEnd = (int)rps[32];
  int eblk = rEnd - r00;
  bool fits = (eblk <= EDGE_CAP);
  if (fits){
    for (int p = tid; p < eblk; p += 256) snb[p] = eidx[r00 + p];
  }
  __syncthreads();

  const unsigned short* lutc = lut_i + c;
  const unsigned short* xc = xsrc_in + c;
  for (int m = hh*16; m < hh*16+16; m++){
    int n = n0 + m;
    float a0=0.f, a1=0.f, a2=0.f, a3=0.f;
    int dg = 1;
    if (n < ndst){
      ab[m][c] = xdst_in[(size_t)n*128 + c];
      int r0 = (int)rps[m], r1 = (int)rps[m+1];
      dg = r1 - r0;
      int p = r0;
      for (; p + 3 < r1; p += 4){
        int v0,v1,v2,v3;
        if (fits){
          v0 = snb[p-r00]; v1 = snb[p-r00+1]; v2 = snb[p-r00+2]; v3 = snb[p-r00+3];
        } else {
          v0 = eidx[p]; v1 = eidx[p+1]; v2 = eidx[p+2]; v3 = eidx[p+3];
        }
        a0 += bf2f(lutc[(size_t)((unsigned)v0 >> 18)*128]) * bf2f(xc[(size_t)(v0 & 0x3FFFF)*128]);
        a1 += bf2f(lutc[(size_t)((unsigned)v1 >> 18)*128]) * bf2f(xc[(size_t)(v1 & 0x3FFFF)*128]);
        a2 += bf2f(lutc[(size_t)((unsigned)v2 >> 18)*128]) * bf2f(xc[(size_t)(v2 & 0x3FFFF)*128]);
        a3 += bf2f(lutc[(size_t)((unsigned)v3 >> 18)*128]) * bf2f(xc[(size_t)(v3 & 0x3FFFF)*128]);
      }
      for (; p < r1; p++){
        int v0 = fits ? snb[p-r00] : eidx[p];
        a0 += bf2f(lutc[(size_t)((unsigned)v0 >> 18)*128]) * bf2f(xc[(size_t)(v0 & 0x3FFFF)*128]);
      }
    } else {
      ab[m][c] = 0;
    }
    float inv = 1.f / (float)(dg > 1 ? dg : 1);
    ab[m][128 + c] = f2bf(((a0+a1)+(a2+a3)) * inv);
  }
  __syncthreads();

  int wave = tid >> 6, lane = tid & 63, quad = lane >> 4, l15 = lane & 15;
  int mt = wave & 1, nh = wave >> 1;
  int arow = mt*16 + l15;
  float4v acc[4] = {{0,0,0,0},{0,0,0,0},{0,0,0,0},{0,0,0,0}};
  for (int k0 = 0; k0 < 256; k0 += 32){
    short8 A = *(const short8*)&ab[arow][k0 + quad*8];
    #pragma unroll
    for (int nt=0;nt<4;nt++){
      short8 B = *(const short8*)&wcat[(size_t)(nh*64 + nt*16 + l15)*256 + k0 + quad*8];
      acc[nt] = __builtin_amdgcn_mfma_f32_16x16x32_bf16(A, B, acc[nt], 0, 0, 0);
    }
  }
  #pragma unroll
  for (int nt=0;nt<4;nt++){
    int col = nh*64 + nt*16 + l15;
    float bc = bias[col];
    #pragma unroll
    for (int r=0;r<4;r++){
      int row = mt*16 + quad*4 + r;
      float v = acc[nt][r] + bc;
      ob[row][col] = f2bf((v > 0.f) ? v : 0.01f*v);    // leaky_relu
    }
  }
  __syncthreads();
  for (int m = hh*16; m < hh*16+16; m++){
    int n = n0 + m;
    if (n < ndst){
      unsigned short vb = ob[m][c];
      size_t off = (size_t)n*128 + c;
      xout[off] = vb;
      xsum[off] = first ? vb : f2bf(bf2f(xsum[off]) + bf2f(vb));
    }
  }
}

// ---- merged MFMA hproj: blocks [0,NBL): ligand (+b1); [NBL,NBL+NBP): protein
__global__ __launch_bounds__(256) void k_hproj2(
    const unsigned short* __restrict__ xl_s, const unsigned short* __restrict__ xp_s,
    const unsigned short* __restrict__ w1t, const float* __restrict__ b1,
    unsigned* __restrict__ h_l, unsigned* __restrict__ h_p){
  __shared__ unsigned short hb[32][528];
  bool isL = blockIdx.x < NBL;
  const unsigned short* xs = isL ? xl_s : xp_s;
  const unsigned short* wt = isL ? w1t : w1t + 65536;
  unsigned* hout = isL ? h_l : h_p;
  int nn = isL ? NLn : NPn;
  int n0 = (isL ? blockIdx.x : blockIdx.x - NBL)*32;
  int tid = threadIdx.x;
  int wave = tid >> 6, lane = tid & 63, quad = lane >> 4, l15 = lane & 15;
  int mt = wave & 1, nh = wave >> 1;
  int an = n0 + mt*16 + l15; if (an >= nn) an = nn - 1;
  const unsigned short* aptr = xs + (size_t)an*128;
  float4v acc[16];
  #pragma unroll
  for (int i=0;i<16;i++) acc[i] = (float4v){0,0,0,0};
  for (int k0 = 0; k0 < 128; k0 += 32){
    short8 A = *(const short8*)&aptr[k0 + quad*8];
    #pragma unroll
    for (int nt=0;nt<16;nt++){
      short8 B = *(const short8*)&wt[(size_t)(nh*256 + nt*16 + l15)*128 + k0 + quad*8];
      acc[nt] = __builtin_amdgcn_mfma_f32_16x16x32_bf16(A, B, acc[nt], 0, 0, 0);
    }
  }
  #pragma unroll
  for (int nt=0;nt<16;nt++){
    int col = nh*256 + nt*16 + l15;
    float bv = isL ? b1[col] : 0.f;
    #pragma unroll
    for (int r=0;r<4;r++) hb[mt*16 + quad*4 + r][col] = f2bf(acc[nt][r] + bv);
  }
  __syncthreads();
  for (int m=0;m<32;m++){
    int n = n0 + m;
    if (n < nn){
      unsigned pack = (unsigned)hb[m][2*tid] | ((unsigned)hb[m][2*tid+1] << 16);
      hout[(size_t)n*256 + tid] = pack;
    }
  }
}

// ---- readout v4: 32 edges/block; 32768B LDS (exactly 5 blocks/CU);
//      chunked+xor-swizzled hbuf; edge metadata in wave regs via shfl;
//      (M32,N32) wave tiles; m in registers; shuffle flush. b1 folded into h_l.
__global__ __launch_bounds__(256, 5) void k_readout4(
    const unsigned* __restrict__ hl, const unsigned* __restrict__ hp,
    const uint4* __restrict__ edgeL, const float* __restrict__ vvec,
    const unsigned short* __restrict__ w2t, const float* __restrict__ b2,
    const unsigned short* __restrict__ wmt, const float* __restrict__ bm,
    float* __restrict__ outw, unsigned* __restrict__ mmax){
  // 32768 B: phase 1 = chunked hbuf (kc<64, edge<32 xor-swizzled, 8 shorts);
  //          phase 2 = msb[32][136] (aliases)
  __shared__ __align__(16) unsigned short lds[16384];
  unsigned short (*msb)[136] = (unsigned short(*)[136])lds;
  int tid = threadIdx.x, lane = tid & 63;
  int e0 = blockIdx.x*32;
  int s_r = 0, d_r = 0, b_r = 0; float dd_r = 0.f;
  {
    int li = lane & 31;
    uint4 er = edgeL[e0 + li];    // lanes 32-63 duplicate 0-31; shfl uses 0-31
    s_r = (int)er.x; d_r = (int)er.y; dd_r = __uint_as_float(er.z); b_r = (int)er.w;
  }
  int j2 = tid*2;
  float2 vv = *(const float2*)&vvec[j2];
  int kc = tid >> 2;               // chunk owned by this thread (cols 8kc..8kc+8)
  int pos = j2 & 7;
  int sw = kc & 31;
  #pragma unroll 8
  for (int i=0;i<32;i++){
    int si = __shfl(s_r, i), di = __shfl(d_r, i);
    float dd = __shfl(dd_r, i);
    unsigned ua = hl[(size_t)si*256 + tid];
    unsigned ub = hp[(size_t)di*256 + tid];
    float hx = fmaxf(bflo(ua) + bflo(ub) + dd*vv.x, 0.f);
    float hy = fmaxf(bfhi(ua) + bfhi(ub) + dd*vv.y, 0.f);
    lds[kc*256 + ((i ^ sw) << 3) + pos] = 0;  // placeholder overwritten below (keeps alignment clear)
    *(unsigned*)&lds[kc*256 + ((i ^ sw) << 3) + pos] =
        (unsigned)f2bf(hx) | ((unsigned)f2bf(hy) << 16);
  }
  __syncthreads();
  int wave = tid >> 6, quad = lane >> 4, l15 = lane & 15;
  int ns = wave*32;                // each wave: M=32 (all edges), N-strip of 32

  // GEMM1: m[32,128] = h[32,512] @ W2^T + b2
  float4v acc[2][2] = {{{0,0,0,0},{0,0,0,0}},{{0,0,0,0},{0,0,0,0}}};
  for (int k0 = 0; k0 < 512; k0 += 32){
    int kcc = (k0 >> 3) + quad;
    int sw2 = kcc & 31;
    short8 A0 = *(const short8*)&lds[kcc*256 + ((l15 ^ sw2) << 3)];
    short8 A1 = *(const short8*)&lds[kcc*256 + (((16 + l15) ^ sw2) << 3)];
    short8 B0 = *(const short8*)&w2t[(size_t)(ns + l15)*512 + k0 + quad*8];
    short8 B1 = *(const short8*)&w2t[(size_t)(ns + 16 + l15)*512 + k0 + quad*8];
    acc[0][0] = __builtin_amdgcn_mfma_f32_16x16x32_bf16(A0, B0, acc[0][0], 0, 0, 0);
    acc[0][1] = __builtin_amdgcn_mfma_f32_16x16x32_bf16(A0, B1, acc[0][1], 0, 0, 0);
    acc[1][0] = __builtin_amdgcn_mfma_f32_16x16x32_bf16(A1, B0, acc[1][0], 0, 0, 0);
    acc[1][1] = __builtin_amdgcn_mfma_f32_16x16x32_bf16(A1, B1, acc[1][1], 0, 0, 0);
  }
  __syncthreads();   // all waves done reading hbuf; msb may overwrite
  float mreg[2][2][4];
  float b2c0 = b2[ns + l15], b2c1 = b2[ns + 16 + l15];
  #pragma unroll
  for (int mt=0;mt<2;mt++){
    #pragma unroll
    for (int nt=0;nt<2;nt++){
      float b2c = nt ? b2c1 : b2c0;
      int col = ns + nt*16 + l15;
      #pragma unroll
      for (int r=0;r<4;r++){
        float mv = acc[mt][nt][r] + b2c;
        mreg[mt][nt][r] = mv;
        msb[mt*16 + quad*4 + r][col] = f2bf(mv);
      }
    }
  }
  __syncthreads();

  // GEMM2: t = tanh(m@Wm^T + bm); flush sum(t*m), max(m) per batch
  float4v acc2[2][2] = {{{0,0,0,0},{0,0,0,0}},{{0,0,0,0},{0,0,0,0}}};
  for (int k0 = 0; k0 < 128; k0 += 32){
    short8 A0 = *(const short8*)&msb[l15][k0 + quad*8];
    short8 A1 = *(const short8*)&msb[16 + l15][k0 + quad*8];
    short8 B0 = *(const short8*)&wmt[(size_t)(ns + l15)*128 + k0 + quad*8];
    short8 B1 = *(const short8*)&wmt[(size_t)(ns + 16 + l15)*128 + k0 + quad*8];
    acc2[0][0] = __builtin_amdgcn_mfma_f32_16x16x32_bf16(A0, B0, acc2[0][0], 0, 0, 0);
    acc2[0][1] = __builtin_amdgcn_mfma_f32_16x16x32_bf16(A0, B1, acc2[0][1], 0, 0, 0);
    acc2[1][0] = __builtin_amdgcn_mfma_f32_16x16x32_bf16(A1, B0, acc2[1][0], 0, 0, 0);
    acc2[1][1] = __builtin_amdgcn_mfma_f32_16x16x32_bf16(A1, B1, acc2[1][1], 0, 0, 0);
  }
  float bm0 = bm[ns + l15], bm1 = bm[ns + 16 + l15];
  int b0 = __shfl(b_r, 0);
  bool uni = (b0 == __shfl(b_r, 31));
  #pragma unroll
  for (int nt=0;nt<2;nt++){
    int col = ns + nt*16 + l15;
    float bmc = nt ? bm1 : bm0;
    if (uni){
      float s = 0.f, mx = -3.402823466e38f;
      #pragma unroll
      for (int mt=0;mt<2;mt++){
        #pragma unroll
        for (int r=0;r<4;r++){
          float mv = mreg[mt][nt][r];
          float t = tanh_fast(acc2[mt][nt][r] + bmc);
          s += t*mv; mx = fmaxf(mx, mv);
        }
      }
      s += __shfl_xor(s, 16); s += __shfl_xor(s, 32);
      mx = fmaxf(mx, __shfl_xor(mx, 16)); mx = fmaxf(mx, __shfl_xor(mx, 32));
      if (quad == 0){
        atomicAdd(&outw[b0*256 + col], s);
        atomicMax(&mmax[b0*128 + col], encf(mx));
      }
    } else {
      #pragma unroll
      for (int mt=0;mt<2;mt++){
        #pragma unroll
        for (int r=0;r<4;r++){
          int row = mt*16 + quad*4 + r;
          int b = __shfl(b_r, row);
          float mv = mreg[mt][nt][r];
          float t = tanh_fast(acc2[mt][nt][r] + bmc);
          atomicAdd(&outw[b*256 + col], t*mv);
          atomicMax(&mmax[b*128 + col], encf(mv));
        }
      }
    }
  }
}

__global__ __launch_bounds__(256) void k_final(const unsigned* __restrict__ mmax,
    float* __restrict__ out){
  int gid = blockIdx.x*256 + threadIdx.x;   // 32768 = 256*128
  unsigned enc = mmax[gid];
  float v;
  if (enc == 0u) v = 0.f;
  else if (enc & 0x80000000u) v = __uint_as_float(enc & 0x7FFFFFFFu);
  else v = __uint_as_float(~enc);
  int g = gid >> 7, cc = gid & 127;
  out[g*256 + 128 + cc] = v;
}

extern "C" void kernel_launch(void* const* d_in, const int* in_sizes, int n_in,
                              void* d_out, int out_size, void* d_ws, size_t ws_size,
                              hipStream_t stream) {
  const float* x_l    = (const float*)d_in[0];
  const float* x_p    = (const float*)d_in[1];
  const float* ea     = (const float*)d_in[2];
  const int*   esrc   = (const int*)d_in[3];
  const int*   edst   = (const int*)d_in[4];
  const int*   lbatch = (const int*)d_in[5];
  const float* W_node = (const float*)d_in[6];
  const float* W_el   = (const float*)d_in[7];
  const float* Wb     = (const float*)d_in[8];
  const float* bb     = (const float*)d_in[9];
  const float* Wn     = (const float*)d_in[10];
  const float* Ws     = (const float*)d_in[11];
  const float* bconv  = (const float*)d_in[12];
  const float* W1     = (const float*)d_in[13];
  const float* b1     = (const float*)d_in[14];
  const float* W2     = (const float*)d_in[15];
  const float* b2     = (const float*)d_in[16];
  const float* Wm     = (const float*)d_in[17];
  const float* bm     = (const float*)d_in[18];

  // ---- workspace layout (decimal offsets), peak 267,354,496 B ----
  char* w = (char*)d_ws;
  unsigned short* xl0 = (unsigned short*)(w + 0);
  unsigned short* xl1 = (unsigned short*)(w + 12800000);
  unsigned short* xp0 = (unsigned short*)(w + 25600000);
  unsigned short* xp1 = (unsigned short*)(w + 64000000);
  int*      idxP  = (int*)(w + 102400000);
  int*      idxL  = (int*)(w + 104400000);
  unsigned short* lut = (unsigned short*)(w + 106400000);   // 6.29e6 B
  unsigned* h_l   = (unsigned*)(w + 0);
  unsigned* h_p   = (unsigned*)(w + 51200000);
  unsigned short* xl_s = (unsigned short*)(w + 204800000);
  unsigned short* xp_s = (unsigned short*)(w + 217600000);
  unsigned short* wcat = (unsigned short*)(w + 256000000);
  unsigned short* w1t  = (unsigned short*)(w + 256393216);
  unsigned short* w2t  = (unsigned short*)(w + 256655360);
  unsigned short* wmt  = (unsigned short*)(w + 256786432);
  float*    vvec  = (float*)(w + 256819200);
  unsigned* mmax  = (unsigned*)(w + 256821248);
  unsigned* bsumL = (unsigned*)(w + 256952320);
  unsigned* bsumP = (unsigned*)(w + 256953344);
  unsigned* rowptrL = (unsigned*)(w + 256954368);
  unsigned* cursorL = (unsigned*)(w + 257154432);
  unsigned* rowptrP = (unsigned*)(w + 257354432);
  unsigned* cursorP = (unsigned*)(w + 257954496);
  unsigned* cntL    = (unsigned*)(w + 258554496);
  unsigned* cntP    = (unsigned*)(w + 258754496);
  uint4*    edgeL   = (uint4*)(w + 259354496);   // {src, dst, bits(d), batch}

  float* out = (float*)d_out;

  k_prep<<<114470, 256, 0, stream>>>(
      (unsigned*)(w + 258554496), mmax, (unsigned*)d_out,
      x_l, x_p, W_node, xl0, xp0,
      W_el, W1, vvec, W2, w2t, Wm, wmt, Ws, Wn, wcat, w1t, Wb, bb, lut);

  k_count<<<1954, 256, 0, stream>>>(esrc, edst, cntL, cntP);
  k_cs2<<<196, 256, 0, stream>>>(cntL, rowptrL, bsumL, cntP, rowptrP, bsumP);
  k_sb2<<<2, 256, 0, stream>>>(bsumL, bsumP);
  k_ao2<<<782, 256, 0, stream>>>(rowptrL, cursorL, bsumL, rowptrP, cursorP, bsumP);
  k_place<<<1954, 256, 0, stream>>>(esrc, edst, ea, lbatch, cursorL, cursorP,
                                    edgeL, idxL, idxP);

  unsigned short *xlc = xl0, *xln = xl1, *xpc = xp0, *xpn = xp1;
  for (int l = 0; l < 3; ++l){
    int ilp = 2*l, ipl = 2*l + 1;
    k_conv2<<<NBP + NBL, 256, 0, stream>>>(
        xpc, xlc, xpn, xln, xp_s, xl_s,
        rowptrP, idxP, rowptrL, idxL,
        lut + (size_t)ilp*524288, wcat + ilp*32768, bconv + ilp*128,
        lut + (size_t)ipl*524288, wcat + ipl*32768, bconv + ipl*128,
        (l == 0) ? 1 : 0);
    unsigned short* t;
    t = xlc; xlc = xln; xln = t;
    t = xpc; xpc = xpn; xpn = t;
  }

  // b1 folded into h_l (ligand part); protein part no bias
  k_hproj2<<<NBL + NBP, 256, 0, stream>>>(xl_s, xp_s, w1t, b1, h_l, h_p);

  k_readout4<<<En/32, 256, 0, stream>>>(h_l, h_p, edgeL, vvec,
                                        w2t, b2, wmt, bm, out, mmax);
  k_final<<<128, 256, 0, stream>>>(mmax, out);
}